// Round 12
// baseline (83.367 us; speedup 1.0000x reference)
//
#include <hip/hip_runtime.h>
#include <math.h>

#define SS 112
#define HW (SS*SS)
#define NPIX (2*HW)   // B*S*S = 25088

typedef __bf16 v8bf __attribute__((ext_vector_type(8)));
typedef short  v8s  __attribute__((ext_vector_type(8)));
typedef float  v4f  __attribute__((ext_vector_type(4)));

__device__ __forceinline__ unsigned short f2bf(float f){
  unsigned u = __builtin_bit_cast(unsigned, f);
  u = (u + 0x7fffu + ((u >> 16) & 1u)) >> 16;
  return (unsigned short)u;
}
__device__ __forceinline__ unsigned cvt_pk_bf16(float lo, float hi){
  unsigned r;
  asm("v_cvt_pk_bf16_f32 %0, %1, %2" : "=v"(r) : "v"(lo), "v"(hi));
  return r;
}
__device__ __forceinline__ v8bf zero8(){
  v8s z = {0,0,0,0,0,0,0,0};
  return __builtin_bit_cast(v8bf, z);
}
__device__ __forceinline__ float gelu_fast(float x){
  float u = fmaf(0.044715f*x, x, 1.0f);
  float z = fminf(2.3021178f * x * u, 80.0f);
  float s = exp2f(z);
  return x * s * __builtin_amdgcn_rcpf(s + 1.0f);
}

struct Params {
  const float *xq, *xkv, *cws, *cwl, *Wq, *Wk, *Wv, *Wo, *W1, *W2, *rpb;
  const float *cbs, *g_s, *b_s, *cbl, *g_l, *b_l;
  const float *bq, *bk, *bv, *bo, *gn, *bn, *b1, *b2;
  unsigned short *WBs, *WBl, *WBq, *WBk, *WBv, *WBo, *WB1, *WB2;
  float *rpb2g;
  unsigned short *xTq, *xTkv, *qb, *kb, *vT, *aob;
  float *emb, *outp;
};

__device__ __forceinline__ void pack_wconv(const float* __restrict__ w,
                                           unsigned short* __restrict__ WB, int idx){
  int lane = idx & 63, tslot = (idx >> 6) & 3, kk = idx >> 8;
  int tap = kk >> 1;
  int ic0 = ((kk & 1) << 5) + ((lane >> 4) << 3);
  int oc  = tslot*16 + (lane & 15);
  union { unsigned short u[8]; uint4 q; } pk;
  #pragma unroll
  for (int i = 0; i < 8; ++i) pk.u[i] = f2bf(w[(oc*64 + ic0 + i)*9 + tap]);
  ((uint4*)WB)[idx] = pk.q;
}
__device__ __forceinline__ void pack_wlin(const float* __restrict__ W,
                                          unsigned short* __restrict__ WB,
                                          int N, int idx){
  int lane = idx & 63;
  int tmp = idx >> 6;
  int tiles = N >> 4;
  int tslot = tmp % tiles;
  int kk = tmp / tiles;
  int k0 = kk*32 + ((lane >> 4) << 3);
  int oc = tslot*16 + (lane & 15);
  union { unsigned short u[8]; uint4 q; } pk;
  #pragma unroll
  for (int i = 0; i < 8; ++i) pk.u[i] = f2bf(W[(size_t)(k0 + i)*N + oc]);
  ((uint4*)WB)[idx] = pk.q;
}

// =============== kernel 1: weight packs + x transpose (grid 839) ============
__global__ __launch_bounds__(256) void k_prep_s(Params P)
{
  __shared__ float tile[64][68];
  const int u = blockIdx.x, tid = threadIdx.x;
  if (u >= 784){
    const int pu = u - 784;   // 0..54
    if      (pu < 18) pack_wconv(P.cws, P.WBs, pu*256 + tid);
    else if (pu < 36) pack_wconv(P.cwl, P.WBl, (pu-18)*256 + tid);
    else if (pu < 38) pack_wlin(P.Wq, P.WBq, 64,  (pu-36)*256 + tid);
    else if (pu < 40) pack_wlin(P.Wk, P.WBk, 64,  (pu-38)*256 + tid);
    else if (pu < 42) pack_wlin(P.Wv, P.WBv, 64,  (pu-40)*256 + tid);
    else if (pu < 44) pack_wlin(P.Wo, P.WBo, 64,  (pu-42)*256 + tid);
    else if (pu < 48) pack_wlin(P.W1, P.WB1, 128, (pu-44)*256 + tid);
    else if (pu < 52) pack_wlin(P.W2, P.WB2, 64,  (pu-48)*256 + tid);
    else {
      int idx = (pu-52)*256 + tid;
      if (idx < 4*169) P.rpb2g[idx] = P.rpb[idx] * 1.4426950408889634f;
    }
    return;
  }
  const int inst = u >= 392 ? 1 : 0;
  const float* x = inst ? P.xkv : P.xq;
  unsigned short* xT = inst ? P.xTkv : P.xTq;
  const int base = (u - inst*392) * 64;
  const int b = base / HW;
  const int r0 = base - b*HW;
  {
    const int cc = tid >> 2, xo = (tid & 3) << 4;
    const float* src = x + ((size_t)(b*64 + cc))*HW + r0 + xo;
    float4 v0 = ((const float4*)src)[0];
    float4 v1 = ((const float4*)src)[1];
    float4 v2 = ((const float4*)src)[2];
    float4 v3 = ((const float4*)src)[3];
    float* dst = &tile[cc][xo];
    ((float4*)dst)[0] = v0; ((float4*)dst)[1] = v1;
    ((float4*)dst)[2] = v2; ((float4*)dst)[3] = v3;
  }
  __syncthreads();
  {
    const int px = tid >> 2, co = (tid & 3) << 4;
    union { unsigned short uu[16]; uint4 q[2]; } pk;
    #pragma unroll
    for (int i = 0; i < 16; ++i) pk.uu[i] = f2bf(tile[co + i][px]);
    uint4* dst = (uint4*)(xT + ((size_t)(base + px))*64 + co);
    dst[0] = pk.q[0]; dst[1] = pk.q[1];
  }
}

// ======== kernel 2: conv(3x3 MFMA) + LN + projections (grid 784) ============
__global__ __launch_bounds__(256) void k_conv_s(Params P)
{
  __shared__ unsigned short nlds4[4][1024];
  const int tid = threadIdx.x;
  const int wid = tid >> 6, l = tid & 63;
  const int g = l >> 4, c = l & 15;
  unsigned short* nlds = nlds4[wid];
  const int u = (blockIdx.x & 7)*98 + (blockIdx.x >> 3);   // bijective: 784 = 8*98
  const int inst = u >= 392 ? 1 : 0;
  const int P0 = ((u - inst*392)*4 + wid) * 16;

  const unsigned short* xT  = inst ? P.xTkv : P.xTq;
  const unsigned short* WBc = inst ? P.WBl : P.WBs;
  const float* cb    = inst ? P.cbl : P.cbs;
  const float* gamma = inst ? P.g_l : P.g_s;
  const float* beta  = inst ? P.b_l : P.b_s;

  const int p = P0 + c;
  const int b = p / HW, r = p - b*HW;
  const int py = r / SS, pxx = r - py*SS;
  const int pb64 = b*HW;

  float cbv[4], gv[4], bev[4];
  #pragma unroll
  for (int t = 0; t < 4; ++t){
    cbv[t] = cb[c + 16*t]; gv[t] = gamma[c + 16*t]; bev[t] = beta[c + 16*t];
  }

  v4f acc[4];
  #pragma unroll
  for (int t = 0; t < 4; ++t) acc[t] = (v4f){cbv[t], cbv[t], cbv[t], cbv[t]};

  const int icg = g << 3;
  #pragma unroll
  for (int kk = 0; kk < 18; ++kk){
    const int tap = kk >> 1;
    const int dy = tap/3 - 1, dx = tap - (tap/3)*3 - 1;
    const int icof = ((kk & 1) << 5) + icg;
    int yy = py + dy, xx = pxx + dx;
    bool ok = ((unsigned)yy < SS) && ((unsigned)xx < SS);
    v8bf a = zero8();
    if (ok) a = *(const v8bf*)(xT + ((size_t)(pb64 + yy*SS + xx))*64 + icof);
    #pragma unroll
    for (int t = 0; t < 4; ++t){
      v8bf bfr = *(const v8bf*)(WBc + ((size_t)((kk*4 + t)*64 + l))*8);
      acc[t] = __builtin_amdgcn_mfma_f32_16x16x32_bf16(a, bfr, acc[t], 0, 0, 0);
    }
  }

  if (inst){
    #pragma unroll
    for (int t = 0; t < 4; ++t)
      #pragma unroll
      for (int r2 = 0; r2 < 4; ++r2)
        P.emb[((size_t)(P0 + 4*g + r2))*64 + c + 16*t] = acc[t][r2];
  }

  {
    float mean[4], inv[4];
    #pragma unroll
    for (int r2 = 0; r2 < 4; ++r2){
      float s = acc[0][r2] + acc[1][r2] + acc[2][r2] + acc[3][r2];
      s += __shfl_xor(s, 1, 64); s += __shfl_xor(s, 2, 64);
      s += __shfl_xor(s, 4, 64); s += __shfl_xor(s, 8, 64);
      mean[r2] = s * (1.f/64.f);
      float d0 = acc[0][r2] - mean[r2], d1 = acc[1][r2] - mean[r2];
      float d2 = acc[2][r2] - mean[r2], d3 = acc[3][r2] - mean[r2];
      float vs = d0*d0 + d1*d1 + d2*d2 + d3*d3;
      vs += __shfl_xor(vs, 1, 64); vs += __shfl_xor(vs, 2, 64);
      vs += __shfl_xor(vs, 4, 64); vs += __shfl_xor(vs, 8, 64);
      inv[r2] = rsqrtf(vs * (1.f/64.f) + 1e-5f);
    }
    #pragma unroll
    for (int t = 0; t < 4; ++t){
      int c16 = 2*t + (c >> 3);
      #pragma unroll
      for (int r2 = 0; r2 < 4; r2 += 2){
        int row0 = 4*g + r2, row1 = row0 + 1;
        float n0 = (acc[t][r2]   - mean[r2])   * inv[r2]   * gv[t] + bev[t];
        float n1 = (acc[t][r2+1] - mean[r2+1]) * inv[r2+1] * gv[t] + bev[t];
        unsigned w = cvt_pk_bf16(n0, n1);
        nlds[row0*64 + (((c16 ^ (row0 & 7)) << 3) | (c & 7))] = (unsigned short)(w & 0xffffu);
        nlds[row1*64 + (((c16 ^ (row1 & 7)) << 3) | (c & 7))] = (unsigned short)(w >> 16);
      }
    }
  }

  #pragma unroll
  for (int which = 0; which < 2; ++which){
    if (which == 1 && !inst) break;
    const unsigned short* WB = which ? P.WBv : (inst ? P.WBk : P.WBq);
    const float* bias        = which ? P.bv : (inst ? P.bk : P.bq);

    float pb[4];
    #pragma unroll
    for (int t = 0; t < 4; ++t) pb[t] = bias[c + 16*t];
    v4f pa[4];
    #pragma unroll
    for (int t = 0; t < 4; ++t) pa[t] = (v4f){pb[t], pb[t], pb[t], pb[t]};

    #pragma unroll
    for (int kk = 0; kk < 2; ++kk){
      v8bf av = *(const v8bf*)(nlds + c*64 + (((kk*4 + g) ^ (c & 7)) << 3));
      #pragma unroll
      for (int t = 0; t < 4; ++t){
        v8bf bfr = *(const v8bf*)(WB + ((size_t)((kk*4 + t)*64 + l))*8);
        pa[t] = __builtin_amdgcn_mfma_f32_16x16x32_bf16(av, bfr, pa[t], 0, 0, 0);
      }
    }
    if (which == 0){
      unsigned short* outp = inst ? P.kb : P.qb;
      #pragma unroll
      for (int t = 0; t < 4; ++t)
        #pragma unroll
        for (int r2 = 0; r2 < 4; r2 += 2){
          unsigned w = cvt_pk_bf16(pa[t][r2], pa[t][r2+1]);
          outp[((size_t)(P0 + 4*g + r2))*64 + c + 16*t]   = (unsigned short)(w & 0xffffu);
          outp[((size_t)(P0 + 4*g + r2+1))*64 + c + 16*t] = (unsigned short)(w >> 16);
        }
    } else {
      #pragma unroll
      for (int t = 0; t < 4; ++t){
        uint2 w2;
        w2.x = cvt_pk_bf16(pa[t][0], pa[t][1]);
        w2.y = cvt_pk_bf16(pa[t][2], pa[t][3]);
        *(uint2*)(P.vT + (size_t)(c + 16*t)*NPIX + (P0 + 4*g)) = w2;
      }
    }
  }
}

// ==== kernel 3: neighborhood attention, 2 units/wave ILP (grid 784) =========
__global__ __launch_bounds__(256) void k_natten_s(Params P)
{
  const int l = threadIdx.x & 63;
  const int h = threadIdx.x >> 6;
  const int ub = (blockIdx.x & 7)*98 + (blockIdx.x >> 3);  // bijective: 784 = 8*98
  const int c = l & 15, g = l >> 4;
  const int arow = 8*(c >> 2) + (c & 3);
  const float SC = 0.3606737602222409f;

  int pbase_[2], p0_[2], si_[2], aj_[2], adj_[2];
  const float* bp_[2];
  v8bf bq_[2];

  #pragma unroll
  for (int uu = 0; uu < 2; ++uu){
    const int u = ub*2 + uu;
    const int p0 = u * 16;
    const int b = p0 / HW, r0 = p0 - b*HW;
    const int i = r0 / SS, j0 = r0 - i*SS;
    const int si = min(max(i - 3, 0), SS - 7);
    const int aj = (min(max(j0 - 3, 0), SS - 22)) & ~7;
    const int oi = si - i + 6;
    const int j   = j0 + c;
    const int sjp = min(max(j - 3, 0), SS - 7);
    p0_[uu] = p0; pbase_[uu] = b*HW; si_[uu] = si; aj_[uu] = aj;
    adj_[uu] = 8*g + (aj - sjp);
    bp_[uu]  = P.rpb2g + h*169 + oi*13 + (8*g + aj - j + 6);
    v8bf bq = zero8();
    if (g < 2) bq = *(const v8bf*)(P.qb + (size_t)(p0 + c)*64 + h*16 + 8*g);
    bq_[uu] = bq;
  }

  // ---- QK^T interleaved across the two units ----
  float lt[2][14][4];
  #pragma unroll
  for (int tau = 0; tau < 14; ++tau){
    const int t = tau >> 1;
    #pragma unroll
    for (int uu = 0; uu < 2; ++uu){
      int kpix = pbase_[uu] + (si_[uu] + t)*SS + aj_[uu] + arow + 4*(tau & 1);
      kpix = min(kpix, NPIX - 1);
      v8bf ak = zero8();
      if (g < 2) ak = *(const v8bf*)(P.kb + (size_t)kpix*64 + h*16 + 8*g);
      v4f a0 = {0.f,0.f,0.f,0.f};
      a0 = __builtin_amdgcn_mfma_f32_16x16x32_bf16(ak, bq_[uu], a0, 0, 0, 0);
      lt[uu][tau][0]=a0[0]; lt[uu][tau][1]=a0[1];
      lt[uu][tau][2]=a0[2]; lt[uu][tau][3]=a0[3];
    }
  }

  // ---- mask + bias + softmax, interleaved ----
  float mx4[2][4];
  #pragma unroll
  for (int uu = 0; uu < 2; ++uu)
    #pragma unroll
    for (int r = 0; r < 4; ++r) mx4[uu][r] = -3e38f;
  #pragma unroll
  for (int tau = 0; tau < 14; ++tau){
    const int t = tau >> 1;
    #pragma unroll
    for (int uu = 0; uu < 2; ++uu)
      #pragma unroll
      for (int r = 0; r < 4; ++r){
        const int cc = 4*(tau & 1) + r;
        float bias = bp_[uu][t*13 + cc];
        float lg = fmaf(lt[uu][tau][r], SC, bias);
        lt[uu][tau][r] = ((unsigned)(adj_[uu] + cc) <= 6u) ? lg : -1e30f;
        mx4[uu][r] = fmaxf(mx4[uu][r], lt[uu][tau][r]);
      }
  }
  float inv_[2];
  #pragma unroll
  for (int uu = 0; uu < 2; ++uu){
    float mx = fmaxf(fmaxf(mx4[uu][0], mx4[uu][1]), fmaxf(mx4[uu][2], mx4[uu][3]));
    mx = fmaxf(mx, __shfl_xor(mx, 16, 64));
    mx = fmaxf(mx, __shfl_xor(mx, 32, 64));
    mx4[uu][0] = mx;   // reuse as broadcast max
  }
  float es4[2][4];
  #pragma unroll
  for (int uu = 0; uu < 2; ++uu)
    #pragma unroll
    for (int r = 0; r < 4; ++r) es4[uu][r] = 0.f;
  #pragma unroll
  for (int tau = 0; tau < 14; ++tau)
    #pragma unroll
    for (int uu = 0; uu < 2; ++uu)
      #pragma unroll
      for (int r = 0; r < 4; ++r){
        float pexp = exp2f(lt[uu][tau][r] - mx4[uu][0]);
        lt[uu][tau][r] = pexp;
        es4[uu][r] += pexp;
      }
  #pragma unroll
  for (int uu = 0; uu < 2; ++uu){
    float es = (es4[uu][0] + es4[uu][1]) + (es4[uu][2] + es4[uu][3]);
    es += __shfl_xor(es, 16, 64);
    es += __shfl_xor(es, 32, 64);
    inv_[uu] = 1.0f / es;
  }

  // ---- PV interleaved ----
  const unsigned short* vrow = P.vT + (size_t)(h*16 + c)*NPIX;
  v4f oacc[2];
  oacc[0] = (v4f){0.f,0.f,0.f,0.f};
  oacc[1] = (v4f){0.f,0.f,0.f,0.f};
  #pragma unroll
  for (int t = 0; t < 7; ++t){
    #pragma unroll
    for (int uu = 0; uu < 2; ++uu){
      union { unsigned w[4]; v8bf bf; } pa;
      pa.w[0] = cvt_pk_bf16(lt[uu][2*t][0]*inv_[uu],   lt[uu][2*t][1]*inv_[uu]);
      pa.w[1] = cvt_pk_bf16(lt[uu][2*t][2]*inv_[uu],   lt[uu][2*t][3]*inv_[uu]);
      pa.w[2] = cvt_pk_bf16(lt[uu][2*t+1][0]*inv_[uu], lt[uu][2*t+1][1]*inv_[uu]);
      pa.w[3] = cvt_pk_bf16(lt[uu][2*t+1][2]*inv_[uu], lt[uu][2*t+1][3]*inv_[uu]);
      int vpixb = pbase_[uu] + (si_[uu] + t)*SS + aj_[uu] + 8*g;
      vpixb = min(vpixb, NPIX - 8);
      v8bf bv = *(const v8bf*)(vrow + vpixb);
      oacc[uu] = __builtin_amdgcn_mfma_f32_16x16x32_bf16(pa.bf, bv, oacc[uu], 0, 0, 0);
    }
  }

  #pragma unroll
  for (int uu = 0; uu < 2; ++uu)
    #pragma unroll
    for (int r = 0; r < 4; r += 2){
      unsigned w = cvt_pk_bf16(oacc[uu][r], oacc[uu][r+1]);
      P.aob[(size_t)(p0_[uu] + 4*g + r)*64 + h*16 + c]   = (unsigned short)(w & 0xffffu);
      P.aob[(size_t)(p0_[uu] + 4*g + r+1)*64 + h*16 + c] = (unsigned short)(w >> 16);
    }
}

// ====== kernel 4: Wo + residual + LN + MLP + residual -> NCHW (grid 392) ====
__global__ __launch_bounds__(256) void k_out_s(Params P)
{
  __shared__ __align__(16) unsigned char smem[24576];
  const int tid = threadIdx.x;
  const int wid = tid >> 6, l = tid & 63;
  const int g = l >> 4, c = l & 15;
  unsigned short* ylds = (unsigned short*)smem + wid*1024;
  unsigned short* hlds = (unsigned short*)(smem + 8192) + wid*2048;
  const int P0 = (blockIdx.x*4 + wid) * 16;
  const int b = P0 / HW;
  const int ijb = P0 - b*HW;

  v4f att[4];
  #pragma unroll
  for (int t = 0; t < 4; ++t){
    float bb = P.bo[c + 16*t];
    #pragma unroll
    for (int r = 0; r < 4; ++r)
      att[t][r] = bb + P.emb[((size_t)(P0 + 4*g + r))*64 + c + 16*t];
  }
  #pragma unroll
  for (int kk = 0; kk < 2; ++kk){
    v8bf a = *(const v8bf*)(P.aob + (size_t)(P0 + c)*64 + kk*32 + 8*g);
    #pragma unroll
    for (int t = 0; t < 4; ++t){
      v8bf bfr = *(const v8bf*)(P.WBo + ((size_t)((kk*4 + t)*64 + l))*8);
      att[t] = __builtin_amdgcn_mfma_f32_16x16x32_bf16(a, bfr, att[t], 0, 0, 0);
    }
  }

  {
    float gv[4], bev[4];
    #pragma unroll
    for (int t = 0; t < 4; ++t){ gv[t] = P.gn[c + 16*t]; bev[t] = P.bn[c + 16*t]; }
    float mean[4], inv[4];
    #pragma unroll
    for (int r = 0; r < 4; ++r){
      float s = att[0][r] + att[1][r] + att[2][r] + att[3][r];
      s += __shfl_xor(s, 1, 64); s += __shfl_xor(s, 2, 64);
      s += __shfl_xor(s, 4, 64); s += __shfl_xor(s, 8, 64);
      mean[r] = s * (1.f/64.f);
      float d0 = att[0][r] - mean[r], d1 = att[1][r] - mean[r];
      float d2 = att[2][r] - mean[r], d3 = att[3][r] - mean[r];
      float vs = d0*d0 + d1*d1 + d2*d2 + d3*d3;
      vs += __shfl_xor(vs, 1, 64); vs += __shfl_xor(vs, 2, 64);
      vs += __shfl_xor(vs, 4, 64); vs += __shfl_xor(vs, 8, 64);
      inv[r] = rsqrtf(vs * (1.f/64.f) + 1e-5f);
    }
    #pragma unroll
    for (int t = 0; t < 4; ++t){
      int c16 = 2*t + (c >> 3);
      #pragma unroll
      for (int r = 0; r < 4; r += 2){
        int row0 = 4*g + r, row1 = row0 + 1;
        float n0 = (att[t][r]   - mean[r])   * inv[r]   * gv[t] + bev[t];
        float n1 = (att[t][r+1] - mean[r+1]) * inv[r+1] * gv[t] + bev[t];
        unsigned w = cvt_pk_bf16(n0, n1);
        ylds[row0*64 + (((c16 ^ (row0 & 7)) << 3) | (c & 7))] = (unsigned short)(w & 0xffffu);
        ylds[row1*64 + (((c16 ^ (row1 & 7)) << 3) | (c & 7))] = (unsigned short)(w >> 16);
      }
    }
  }

  v4f hc[8];
  #pragma unroll
  for (int tt = 0; tt < 8; ++tt){
    float bb = P.b1[c + 16*tt];
    hc[tt] = (v4f){bb,bb,bb,bb};
  }
  #pragma unroll
  for (int kk = 0; kk < 2; ++kk){
    v8bf a = *(const v8bf*)(ylds + c*64 + (((kk*4 + g) ^ (c & 7)) << 3));
    #pragma unroll
    for (int tt = 0; tt < 8; ++tt){
      v8bf bfr = *(const v8bf*)(P.WB1 + ((size_t)((kk*8 + tt)*64 + l))*8);
      hc[tt] = __builtin_amdgcn_mfma_f32_16x16x32_bf16(a, bfr, hc[tt], 0, 0, 0);
    }
  }
  #pragma unroll
  for (int tt = 0; tt < 8; ++tt){
    int chunk = 2*tt + (c >> 3);
    #pragma unroll
    for (int r = 0; r < 4; r += 2){
      int row0 = 4*g + r, row1 = row0 + 1;
      int swz0 = (chunk & 8) | ((chunk & 7) ^ (row0 & 7));
      int swz1 = (chunk & 8) | ((chunk & 7) ^ (row1 & 7));
      unsigned w = cvt_pk_bf16(gelu_fast(hc[tt][r]), gelu_fast(hc[tt][r+1]));
      hlds[row0*128 + swz0*8 + (c & 7)] = (unsigned short)(w & 0xffffu);
      hlds[row1*128 + swz1*8 + (c & 7)] = (unsigned short)(w >> 16);
    }
  }

  v4f xc[4];
  #pragma unroll
  for (int t = 0; t < 4; ++t){
    float bb = P.b2[c + 16*t];
    #pragma unroll
    for (int r = 0; r < 4; ++r)
      xc[t][r] = bb + att[t][r];
  }
  #pragma unroll
  for (int kk = 0; kk < 4; ++kk){
    int chunk = 4*kk + g;
    int swz = (chunk & 8) | ((chunk & 7) ^ (c & 7));
    v8bf a = *(const v8bf*)(hlds + c*128 + swz*8);
    #pragma unroll
    for (int t = 0; t < 4; ++t){
      v8bf bfr = *(const v8bf*)(P.WB2 + ((size_t)((kk*4 + t)*64 + l))*8);
      xc[t] = __builtin_amdgcn_mfma_f32_16x16x32_bf16(a, bfr, xc[t], 0, 0, 0);
    }
  }
  #pragma unroll
  for (int t = 0; t < 4; ++t)
    #pragma unroll
    for (int r = 0; r < 4; ++r)
      P.outp[((size_t)(b*64 + c + 16*t))*HW + ijb + 4*g + r] = xc[t][r];
}

extern "C" void kernel_launch(void* const* d_in, const int* in_sizes, int n_in,
                              void* d_out, int out_size, void* d_ws, size_t ws_size,
                              hipStream_t stream) {
  Params P;
  P.xq  = (const float*)d_in[0];
  P.xkv = (const float*)d_in[1];
  P.cws = (const float*)d_in[2];
  P.cbs = (const float*)d_in[3];
  P.cwl = (const float*)d_in[4];
  P.cbl = (const float*)d_in[5];
  P.g_s = (const float*)d_in[6];
  P.b_s = (const float*)d_in[7];
  P.g_l = (const float*)d_in[8];
  P.b_l = (const float*)d_in[9];
  P.Wq  = (const float*)d_in[10];
  P.bq  = (const float*)d_in[11];
  P.Wk  = (const float*)d_in[12];
  P.bk  = (const float*)d_in[13];
  P.Wv  = (const float*)d_in[14];
  P.bv  = (const float*)d_in[15];
  P.Wo  = (const float*)d_in[16];
  P.bo  = (const float*)d_in[17];
  P.rpb = (const float*)d_in[18];
  P.gn  = (const float*)d_in[19];
  P.bn  = (const float*)d_in[20];
  P.W1  = (const float*)d_in[21];
  P.b1  = (const float*)d_in[22];
  P.W2  = (const float*)d_in[23];
  P.b2  = (const float*)d_in[24];

  unsigned short* xTq  = (unsigned short*)d_ws;          // NPIX*64
  unsigned short* xTkv = xTq  + (size_t)NPIX*64;
  unsigned short* WBs  = xTkv + (size_t)NPIX*64;         // 36864
  unsigned short* WBl  = WBs  + 36864;
  unsigned short* WBq  = WBl  + 36864;                   // 4096
  unsigned short* WBk  = WBq  + 4096;
  unsigned short* WBv  = WBk  + 4096;
  unsigned short* WBo  = WBv  + 4096;
  unsigned short* WB1  = WBo  + 4096;                    // 8192
  unsigned short* WB2  = WB1  + 8192;                    // 8192
  unsigned short* qb   = WB2  + 8192;                    // NPIX*64 bf16
  unsigned short* kb   = qb   + (size_t)NPIX*64;
  unsigned short* vT   = kb   + (size_t)NPIX*64;         // transposed [64][NPIX]
  unsigned short* aob  = vT   + (size_t)NPIX*64;         // NPIX*64 bf16
  float* emb   = (float*)(aob + (size_t)NPIX*64);        // NPIX*64 f32
  float* rpb2a = emb + (size_t)NPIX*64;                  // guarded table
  float* rpb2g = rpb2a + 64;

  P.WBs = WBs; P.WBl = WBl; P.WBq = WBq; P.WBk = WBk; P.WBv = WBv;
  P.WBo = WBo; P.WB1 = WB1; P.WB2 = WB2;
  P.rpb2g = rpb2g;
  P.xTq = xTq; P.xTkv = xTkv; P.qb = qb; P.kb = kb; P.vT = vT; P.aob = aob;
  P.emb = emb; P.outp = (float*)d_out;

  hipLaunchKernelGGL(k_prep_s,   dim3(839), dim3(256), 0, stream, P);
  hipLaunchKernelGGL(k_conv_s,   dim3(784), dim3(256), 0, stream, P);
  hipLaunchKernelGGL(k_natten_s, dim3(784), dim3(256), 0, stream, P);
  hipLaunchKernelGGL(k_out_s,    dim3(392), dim3(256), 0, stream, P);
}

// Round 13
// 70.711 us; speedup vs baseline: 1.1790x; 1.1790x over previous
//
#include <hip/hip_runtime.h>
#include <math.h>

#define SS 112
#define HW (SS*SS)
#define NPIX (2*HW)   // B*S*S = 25088

typedef __bf16 v8bf __attribute__((ext_vector_type(8)));
typedef short  v8s  __attribute__((ext_vector_type(8)));
typedef float  v4f  __attribute__((ext_vector_type(4)));

__device__ __forceinline__ unsigned short f2bf(float f){
  unsigned u = __builtin_bit_cast(unsigned, f);
  u = (u + 0x7fffu + ((u >> 16) & 1u)) >> 16;
  return (unsigned short)u;
}
__device__ __forceinline__ unsigned cvt_pk_bf16(float lo, float hi){
  unsigned r;
  asm("v_cvt_pk_bf16_f32 %0, %1, %2" : "=v"(r) : "v"(lo), "v"(hi));
  return r;
}
__device__ __forceinline__ v8bf zero8(){
  v8s z = {0,0,0,0,0,0,0,0};
  return __builtin_bit_cast(v8bf, z);
}
__device__ __forceinline__ float gelu_fast(float x){
  float u = fmaf(0.044715f*x, x, 1.0f);
  float z = fminf(2.3021178f * x * u, 80.0f);
  float s = exp2f(z);
  return x * s * __builtin_amdgcn_rcpf(s + 1.0f);
}

struct Params {
  const float *xq, *xkv, *cws, *cwl, *Wq, *Wk, *Wv, *Wo, *W1, *W2, *rpb;
  const float *cbs, *g_s, *b_s, *cbl, *g_l, *b_l;
  const float *bq, *bk, *bv, *bo, *gn, *bn, *b1, *b2;
  unsigned short *WBs, *WBl, *WBq, *WBk, *WBv, *WBo, *WB1, *WB2;
  float *rpb2g;
  unsigned short *xTq, *xTkv, *qb, *kb, *vT, *aob;
  float *emb, *outp;
};

__device__ __forceinline__ void pack_wconv(const float* __restrict__ w,
                                           unsigned short* __restrict__ WB, int idx){
  int lane = idx & 63, tslot = (idx >> 6) & 3, kk = idx >> 8;
  int tap = kk >> 1;
  int ic0 = ((kk & 1) << 5) + ((lane >> 4) << 3);
  int oc  = tslot*16 + (lane & 15);
  union { unsigned short u[8]; uint4 q; } pk;
  #pragma unroll
  for (int i = 0; i < 8; ++i) pk.u[i] = f2bf(w[(oc*64 + ic0 + i)*9 + tap]);
  ((uint4*)WB)[idx] = pk.q;
}
__device__ __forceinline__ void pack_wlin(const float* __restrict__ W,
                                          unsigned short* __restrict__ WB,
                                          int N, int idx){
  int lane = idx & 63;
  int tmp = idx >> 6;
  int tiles = N >> 4;
  int tslot = tmp % tiles;
  int kk = tmp / tiles;
  int k0 = kk*32 + ((lane >> 4) << 3);
  int oc = tslot*16 + (lane & 15);
  union { unsigned short u[8]; uint4 q; } pk;
  #pragma unroll
  for (int i = 0; i < 8; ++i) pk.u[i] = f2bf(W[(size_t)(k0 + i)*N + oc]);
  ((uint4*)WB)[idx] = pk.q;
}

// =============== kernel 1: weight packs + x transpose (grid 839) ============
__global__ __launch_bounds__(256) void k_prep_s(Params P)
{
  __shared__ float tile[64][68];
  const int u = blockIdx.x, tid = threadIdx.x;
  if (u >= 784){
    const int pu = u - 784;   // 0..54
    if      (pu < 18) pack_wconv(P.cws, P.WBs, pu*256 + tid);
    else if (pu < 36) pack_wconv(P.cwl, P.WBl, (pu-18)*256 + tid);
    else if (pu < 38) pack_wlin(P.Wq, P.WBq, 64,  (pu-36)*256 + tid);
    else if (pu < 40) pack_wlin(P.Wk, P.WBk, 64,  (pu-38)*256 + tid);
    else if (pu < 42) pack_wlin(P.Wv, P.WBv, 64,  (pu-40)*256 + tid);
    else if (pu < 44) pack_wlin(P.Wo, P.WBo, 64,  (pu-42)*256 + tid);
    else if (pu < 48) pack_wlin(P.W1, P.WB1, 128, (pu-44)*256 + tid);
    else if (pu < 52) pack_wlin(P.W2, P.WB2, 64,  (pu-48)*256 + tid);
    else {
      int idx = (pu-52)*256 + tid;
      if (idx < 4*169) P.rpb2g[idx] = P.rpb[idx] * 1.4426950408889634f;
    }
    return;
  }
  const int inst = u >= 392 ? 1 : 0;
  const float* x = inst ? P.xkv : P.xq;
  unsigned short* xT = inst ? P.xTkv : P.xTq;
  const int base = (u - inst*392) * 64;
  const int b = base / HW;
  const int r0 = base - b*HW;
  {
    const int cc = tid >> 2, xo = (tid & 3) << 4;
    const float* src = x + ((size_t)(b*64 + cc))*HW + r0 + xo;
    float4 v0 = ((const float4*)src)[0];
    float4 v1 = ((const float4*)src)[1];
    float4 v2 = ((const float4*)src)[2];
    float4 v3 = ((const float4*)src)[3];
    float* dst = &tile[cc][xo];
    ((float4*)dst)[0] = v0; ((float4*)dst)[1] = v1;
    ((float4*)dst)[2] = v2; ((float4*)dst)[3] = v3;
  }
  __syncthreads();
  {
    const int px = tid >> 2, co = (tid & 3) << 4;
    union { unsigned short uu[16]; uint4 q[2]; } pk;
    #pragma unroll
    for (int i = 0; i < 16; ++i) pk.uu[i] = f2bf(tile[co + i][px]);
    uint4* dst = (uint4*)(xT + ((size_t)(base + px))*64 + co);
    dst[0] = pk.q[0]; dst[1] = pk.q[1];
  }
}

// ======== kernel 2: conv(3x3 MFMA) + LN + projections (grid 784) ============
// XCD-chunked swizzle: 98 consecutive units per XCD for halo/weight L2 reuse.
__global__ __launch_bounds__(256) void k_conv_s(Params P)
{
  __shared__ unsigned short nlds4[4][1024];
  const int tid = threadIdx.x;
  const int wid = tid >> 6, l = tid & 63;
  const int g = l >> 4, c = l & 15;
  unsigned short* nlds = nlds4[wid];
  const int u = (blockIdx.x & 7)*98 + (blockIdx.x >> 3);   // bijective: 784 = 8*98
  const int inst = u >= 392 ? 1 : 0;
  const int P0 = ((u - inst*392)*4 + wid) * 16;

  const unsigned short* xT  = inst ? P.xTkv : P.xTq;
  const unsigned short* WBc = inst ? P.WBl : P.WBs;
  const float* cb    = inst ? P.cbl : P.cbs;
  const float* gamma = inst ? P.g_l : P.g_s;
  const float* beta  = inst ? P.b_l : P.b_s;

  const int p = P0 + c;
  const int b = p / HW, r = p - b*HW;
  const int py = r / SS, pxx = r - py*SS;
  const int pb64 = b*HW;

  float cbv[4], gv[4], bev[4];
  #pragma unroll
  for (int t = 0; t < 4; ++t){
    cbv[t] = cb[c + 16*t]; gv[t] = gamma[c + 16*t]; bev[t] = beta[c + 16*t];
  }

  v4f acc[4];
  #pragma unroll
  for (int t = 0; t < 4; ++t) acc[t] = (v4f){cbv[t], cbv[t], cbv[t], cbv[t]};

  const int icg = g << 3;
  #pragma unroll
  for (int kk = 0; kk < 18; ++kk){
    const int tap = kk >> 1;
    const int dy = tap/3 - 1, dx = tap - (tap/3)*3 - 1;
    const int icof = ((kk & 1) << 5) + icg;
    int yy = py + dy, xx = pxx + dx;
    bool ok = ((unsigned)yy < SS) && ((unsigned)xx < SS);
    v8bf a = zero8();
    if (ok) a = *(const v8bf*)(xT + ((size_t)(pb64 + yy*SS + xx))*64 + icof);
    #pragma unroll
    for (int t = 0; t < 4; ++t){
      v8bf bfr = *(const v8bf*)(WBc + ((size_t)((kk*4 + t)*64 + l))*8);
      acc[t] = __builtin_amdgcn_mfma_f32_16x16x32_bf16(a, bfr, acc[t], 0, 0, 0);
    }
  }

  if (inst){
    #pragma unroll
    for (int t = 0; t < 4; ++t)
      #pragma unroll
      for (int r2 = 0; r2 < 4; ++r2)
        P.emb[((size_t)(P0 + 4*g + r2))*64 + c + 16*t] = acc[t][r2];
  }

  {
    float mean[4], inv[4];
    #pragma unroll
    for (int r2 = 0; r2 < 4; ++r2){
      float s = acc[0][r2] + acc[1][r2] + acc[2][r2] + acc[3][r2];
      s += __shfl_xor(s, 1, 64); s += __shfl_xor(s, 2, 64);
      s += __shfl_xor(s, 4, 64); s += __shfl_xor(s, 8, 64);
      mean[r2] = s * (1.f/64.f);
      float d0 = acc[0][r2] - mean[r2], d1 = acc[1][r2] - mean[r2];
      float d2 = acc[2][r2] - mean[r2], d3 = acc[3][r2] - mean[r2];
      float vs = d0*d0 + d1*d1 + d2*d2 + d3*d3;
      vs += __shfl_xor(vs, 1, 64); vs += __shfl_xor(vs, 2, 64);
      vs += __shfl_xor(vs, 4, 64); vs += __shfl_xor(vs, 8, 64);
      inv[r2] = rsqrtf(vs * (1.f/64.f) + 1e-5f);
    }
    #pragma unroll
    for (int t = 0; t < 4; ++t){
      int c16 = 2*t + (c >> 3);
      #pragma unroll
      for (int r2 = 0; r2 < 4; r2 += 2){
        int row0 = 4*g + r2, row1 = row0 + 1;
        float n0 = (acc[t][r2]   - mean[r2])   * inv[r2]   * gv[t] + bev[t];
        float n1 = (acc[t][r2+1] - mean[r2+1]) * inv[r2+1] * gv[t] + bev[t];
        unsigned w = cvt_pk_bf16(n0, n1);
        nlds[row0*64 + (((c16 ^ (row0 & 7)) << 3) | (c & 7))] = (unsigned short)(w & 0xffffu);
        nlds[row1*64 + (((c16 ^ (row1 & 7)) << 3) | (c & 7))] = (unsigned short)(w >> 16);
      }
    }
  }

  #pragma unroll
  for (int which = 0; which < 2; ++which){
    if (which == 1 && !inst) break;
    const unsigned short* WB = which ? P.WBv : (inst ? P.WBk : P.WBq);
    const float* bias        = which ? P.bv : (inst ? P.bk : P.bq);

    float pb[4];
    #pragma unroll
    for (int t = 0; t < 4; ++t) pb[t] = bias[c + 16*t];
    v4f pa[4];
    #pragma unroll
    for (int t = 0; t < 4; ++t) pa[t] = (v4f){pb[t], pb[t], pb[t], pb[t]};

    #pragma unroll
    for (int kk = 0; kk < 2; ++kk){
      v8bf av = *(const v8bf*)(nlds + c*64 + (((kk*4 + g) ^ (c & 7)) << 3));
      #pragma unroll
      for (int t = 0; t < 4; ++t){
        v8bf bfr = *(const v8bf*)(WB + ((size_t)((kk*4 + t)*64 + l))*8);
        pa[t] = __builtin_amdgcn_mfma_f32_16x16x32_bf16(av, bfr, pa[t], 0, 0, 0);
      }
    }
    if (which == 0){
      unsigned short* outp = inst ? P.kb : P.qb;
      #pragma unroll
      for (int t = 0; t < 4; ++t)
        #pragma unroll
        for (int r2 = 0; r2 < 4; r2 += 2){
          unsigned w = cvt_pk_bf16(pa[t][r2], pa[t][r2+1]);
          outp[((size_t)(P0 + 4*g + r2))*64 + c + 16*t]   = (unsigned short)(w & 0xffffu);
          outp[((size_t)(P0 + 4*g + r2+1))*64 + c + 16*t] = (unsigned short)(w >> 16);
        }
    } else {
      #pragma unroll
      for (int t = 0; t < 4; ++t){
        uint2 w2;
        w2.x = cvt_pk_bf16(pa[t][0], pa[t][1]);
        w2.y = cvt_pk_bf16(pa[t][2], pa[t][3]);
        *(uint2*)(P.vT + (size_t)(c + 16*t)*NPIX + (P0 + 4*g)) = w2;
      }
    }
  }
}

// ========== kernel 3: neighborhood attention (grid 1568, swizzled) ==========
__global__ __launch_bounds__(256) void k_natten_s(Params P)
{
  const int l = threadIdx.x & 63;
  const int h = threadIdx.x >> 6;
  const int u = (blockIdx.x & 7)*196 + (blockIdx.x >> 3);  // bijective: 1568 = 8*196
  const int c = l & 15, g = l >> 4;
  const int p0 = u * 16;
  const int b = p0 / HW, r0 = p0 - b*HW;
  const int i = r0 / SS, j0 = r0 - i*SS;

  const int si = min(max(i - 3, 0), SS - 7);
  const int aj = (min(max(j0 - 3, 0), SS - 22)) & ~7;
  const int oi = si - i + 6;
  const int pbase = b*HW;

  const int j   = j0 + c;
  const int sjp = min(max(j - 3, 0), SS - 7);
  const int adj = 8*g + (aj - sjp);
  const float* bp = P.rpb2g + h*169 + oi*13 + (8*g + aj - j + 6);

  v8bf bq = zero8();
  if (g < 2) bq = *(const v8bf*)(P.qb + (size_t)(p0 + c)*64 + h*16 + 8*g);

  float lt[14][4];
  const int arow = 8*(c >> 2) + (c & 3);
  #pragma unroll
  for (int tau = 0; tau < 14; ++tau){
    const int t = tau >> 1;
    int kpix = pbase + (si + t)*SS + aj + arow + 4*(tau & 1);
    kpix = min(kpix, NPIX - 1);
    v8bf ak = zero8();
    if (g < 2) ak = *(const v8bf*)(P.kb + (size_t)kpix*64 + h*16 + 8*g);
    v4f a0 = {0.f,0.f,0.f,0.f};
    a0 = __builtin_amdgcn_mfma_f32_16x16x32_bf16(ak, bq, a0, 0, 0, 0);
    lt[tau][0]=a0[0]; lt[tau][1]=a0[1]; lt[tau][2]=a0[2]; lt[tau][3]=a0[3];
  }

  const float SC = 0.3606737602222409f;
  float mx4[4] = {-3e38f,-3e38f,-3e38f,-3e38f};
  #pragma unroll
  for (int tau = 0; tau < 14; ++tau){
    const int t = tau >> 1;
    #pragma unroll
    for (int r = 0; r < 4; ++r){
      const int cc = 4*(tau & 1) + r;
      float bias = bp[t*13 + cc];
      float lg = fmaf(lt[tau][r], SC, bias);
      lt[tau][r] = ((unsigned)(adj + cc) <= 6u) ? lg : -1e30f;
      mx4[r] = fmaxf(mx4[r], lt[tau][r]);
    }
  }
  float mx = fmaxf(fmaxf(mx4[0], mx4[1]), fmaxf(mx4[2], mx4[3]));
  mx = fmaxf(mx, __shfl_xor(mx, 16, 64));
  mx = fmaxf(mx, __shfl_xor(mx, 32, 64));
  float es4[4] = {0.f,0.f,0.f,0.f};
  #pragma unroll
  for (int tau = 0; tau < 14; ++tau)
    #pragma unroll
    for (int r = 0; r < 4; ++r){
      float pexp = exp2f(lt[tau][r] - mx);
      lt[tau][r] = pexp;
      es4[r] += pexp;
    }
  float es = (es4[0] + es4[1]) + (es4[2] + es4[3]);
  es += __shfl_xor(es, 16, 64);
  es += __shfl_xor(es, 32, 64);
  const float inv = 1.0f / es;

  const unsigned short* vrow = P.vT + (size_t)(h*16 + c)*NPIX;
  v4f oacc = {0.f,0.f,0.f,0.f};
  #pragma unroll
  for (int t = 0; t < 7; ++t){
    union { unsigned w[4]; v8bf bf; } pa;
    pa.w[0] = cvt_pk_bf16(lt[2*t][0]*inv,   lt[2*t][1]*inv);
    pa.w[1] = cvt_pk_bf16(lt[2*t][2]*inv,   lt[2*t][3]*inv);
    pa.w[2] = cvt_pk_bf16(lt[2*t+1][0]*inv, lt[2*t+1][1]*inv);
    pa.w[3] = cvt_pk_bf16(lt[2*t+1][2]*inv, lt[2*t+1][3]*inv);
    int vpixb = pbase + (si + t)*SS + aj + 8*g;
    vpixb = min(vpixb, NPIX - 8);
    v8bf bv = *(const v8bf*)(vrow + vpixb);
    oacc = __builtin_amdgcn_mfma_f32_16x16x32_bf16(pa.bf, bv, oacc, 0, 0, 0);
  }

  #pragma unroll
  for (int r = 0; r < 4; r += 2){
    unsigned w = cvt_pk_bf16(oacc[r], oacc[r+1]);
    P.aob[(size_t)(p0 + 4*g + r)*64 + h*16 + c]   = (unsigned short)(w & 0xffffu);
    P.aob[(size_t)(p0 + 4*g + r+1)*64 + h*16 + c] = (unsigned short)(w >> 16);
  }
}

// ====== kernel 4: Wo + residual + LN + MLP + residual -> NCHW (grid 392) ====
__global__ __launch_bounds__(256) void k_out_s(Params P)
{
  __shared__ __align__(16) unsigned char smem[24576];
  const int tid = threadIdx.x;
  const int wid = tid >> 6, l = tid & 63;
  const int g = l >> 4, c = l & 15;
  unsigned short* ylds = (unsigned short*)smem + wid*1024;
  unsigned short* hlds = (unsigned short*)(smem + 8192) + wid*2048;
  const int P0 = (blockIdx.x*4 + wid) * 16;
  const int b = P0 / HW;
  const int ijb = P0 - b*HW;

  v4f att[4];
  #pragma unroll
  for (int t = 0; t < 4; ++t){
    float bb = P.bo[c + 16*t];
    #pragma unroll
    for (int r = 0; r < 4; ++r)
      att[t][r] = bb + P.emb[((size_t)(P0 + 4*g + r))*64 + c + 16*t];
  }
  #pragma unroll
  for (int kk = 0; kk < 2; ++kk){
    v8bf a = *(const v8bf*)(P.aob + (size_t)(P0 + c)*64 + kk*32 + 8*g);
    #pragma unroll
    for (int t = 0; t < 4; ++t){
      v8bf bfr = *(const v8bf*)(P.WBo + ((size_t)((kk*4 + t)*64 + l))*8);
      att[t] = __builtin_amdgcn_mfma_f32_16x16x32_bf16(a, bfr, att[t], 0, 0, 0);
    }
  }

  {
    float gv[4], bev[4];
    #pragma unroll
    for (int t = 0; t < 4; ++t){ gv[t] = P.gn[c + 16*t]; bev[t] = P.bn[c + 16*t]; }
    float mean[4], inv[4];
    #pragma unroll
    for (int r = 0; r < 4; ++r){
      float s = att[0][r] + att[1][r] + att[2][r] + att[3][r];
      s += __shfl_xor(s, 1, 64); s += __shfl_xor(s, 2, 64);
      s += __shfl_xor(s, 4, 64); s += __shfl_xor(s, 8, 64);
      mean[r] = s * (1.f/64.f);
      float d0 = att[0][r] - mean[r], d1 = att[1][r] - mean[r];
      float d2 = att[2][r] - mean[r], d3 = att[3][r] - mean[r];
      float vs = d0*d0 + d1*d1 + d2*d2 + d3*d3;
      vs += __shfl_xor(vs, 1, 64); vs += __shfl_xor(vs, 2, 64);
      vs += __shfl_xor(vs, 4, 64); vs += __shfl_xor(vs, 8, 64);
      inv[r] = rsqrtf(vs * (1.f/64.f) + 1e-5f);
    }
    #pragma unroll
    for (int t = 0; t < 4; ++t){
      int c16 = 2*t + (c >> 3);
      #pragma unroll
      for (int r = 0; r < 4; r += 2){
        int row0 = 4*g + r, row1 = row0 + 1;
        float n0 = (att[t][r]   - mean[r])   * inv[r]   * gv[t] + bev[t];
        float n1 = (att[t][r+1] - mean[r+1]) * inv[r+1] * gv[t] + bev[t];
        unsigned w = cvt_pk_bf16(n0, n1);
        ylds[row0*64 + (((c16 ^ (row0 & 7)) << 3) | (c & 7))] = (unsigned short)(w & 0xffffu);
        ylds[row1*64 + (((c16 ^ (row1 & 7)) << 3) | (c & 7))] = (unsigned short)(w >> 16);
      }
    }
  }

  v4f hc[8];
  #pragma unroll
  for (int tt = 0; tt < 8; ++tt){
    float bb = P.b1[c + 16*tt];
    hc[tt] = (v4f){bb,bb,bb,bb};
  }
  #pragma unroll
  for (int kk = 0; kk < 2; ++kk){
    v8bf a = *(const v8bf*)(ylds + c*64 + (((kk*4 + g) ^ (c & 7)) << 3));
    #pragma unroll
    for (int tt = 0; tt < 8; ++tt){
      v8bf bfr = *(const v8bf*)(P.WB1 + ((size_t)((kk*8 + tt)*64 + l))*8);
      hc[tt] = __builtin_amdgcn_mfma_f32_16x16x32_bf16(a, bfr, hc[tt], 0, 0, 0);
    }
  }
  #pragma unroll
  for (int tt = 0; tt < 8; ++tt){
    int chunk = 2*tt + (c >> 3);
    #pragma unroll
    for (int r = 0; r < 4; r += 2){
      int row0 = 4*g + r, row1 = row0 + 1;
      int swz0 = (chunk & 8) | ((chunk & 7) ^ (row0 & 7));
      int swz1 = (chunk & 8) | ((chunk & 7) ^ (row1 & 7));
      unsigned w = cvt_pk_bf16(gelu_fast(hc[tt][r]), gelu_fast(hc[tt][r+1]));
      hlds[row0*128 + swz0*8 + (c & 7)] = (unsigned short)(w & 0xffffu);
      hlds[row1*128 + swz1*8 + (c & 7)] = (unsigned short)(w >> 16);
    }
  }

  v4f xc[4];
  #pragma unroll
  for (int t = 0; t < 4; ++t){
    float bb = P.b2[c + 16*t];
    #pragma unroll
    for (int r = 0; r < 4; ++r)
      xc[t][r] = bb + att[t][r];
  }
  #pragma unroll
  for (int kk = 0; kk < 4; ++kk){
    int chunk = 4*kk + g;
    int swz = (chunk & 8) | ((chunk & 7) ^ (c & 7));
    v8bf a = *(const v8bf*)(hlds + c*128 + swz*8);
    #pragma unroll
    for (int t = 0; t < 4; ++t){
      v8bf bfr = *(const v8bf*)(P.WB2 + ((size_t)((kk*4 + t)*64 + l))*8);
      xc[t] = __builtin_amdgcn_mfma_f32_16x16x32_bf16(a, bfr, xc[t], 0, 0, 0);
    }
  }
  #pragma unroll
  for (int t = 0; t < 4; ++t)
    #pragma unroll
    for (int r = 0; r < 4; ++r)
      P.outp[((size_t)(b*64 + c + 16*t))*HW + ijb + 4*g + r] = xc[t][r];
}

extern "C" void kernel_launch(void* const* d_in, const int* in_sizes, int n_in,
                              void* d_out, int out_size, void* d_ws, size_t ws_size,
                              hipStream_t stream) {
  Params P;
  P.xq  = (const float*)d_in[0];
  P.xkv = (const float*)d_in[1];
  P.cws = (const float*)d_in[2];
  P.cbs = (const float*)d_in[3];
  P.cwl = (const float*)d_in[4];
  P.cbl = (const float*)d_in[5];
  P.g_s = (const float*)d_in[6];
  P.b_s = (const float*)d_in[7];
  P.g_l = (const float*)d_in[8];
  P.b_l = (const float*)d_in[9];
  P.Wq  = (const float*)d_in[10];
  P.bq  = (const float*)d_in[11];
  P.Wk  = (const float*)d_in[12];
  P.bk  = (const float*)d_in[13];
  P.Wv  = (const float*)d_in[14];
  P.bv  = (const float*)d_in[15];
  P.Wo  = (const float*)d_in[16];
  P.bo  = (const float*)d_in[17];
  P.rpb = (const float*)d_in[18];
  P.gn  = (const float*)d_in[19];
  P.bn  = (const float*)d_in[20];
  P.W1  = (const float*)d_in[21];
  P.b1  = (const float*)d_in[22];
  P.W2  = (const float*)d_in[23];
  P.b2  = (const float*)d_in[24];

  unsigned short* xTq  = (unsigned short*)d_ws;          // NPIX*64
  unsigned short* xTkv = xTq  + (size_t)NPIX*64;
  unsigned short* WBs  = xTkv + (size_t)NPIX*64;         // 36864
  unsigned short* WBl  = WBs  + 36864;
  unsigned short* WBq  = WBl  + 36864;                   // 4096
  unsigned short* WBk  = WBq  + 4096;
  unsigned short* WBv  = WBk  + 4096;
  unsigned short* WBo  = WBv  + 4096;
  unsigned short* WB1  = WBo  + 4096;                    // 8192
  unsigned short* WB2  = WB1  + 8192;                    // 8192
  unsigned short* qb   = WB2  + 8192;                    // NPIX*64 bf16
  unsigned short* kb   = qb   + (size_t)NPIX*64;
  unsigned short* vT   = kb   + (size_t)NPIX*64;         // transposed [64][NPIX]
  unsigned short* aob  = vT   + (size_t)NPIX*64;         // NPIX*64 bf16
  float* emb   = (float*)(aob + (size_t)NPIX*64);        // NPIX*64 f32
  float* rpb2a = emb + (size_t)NPIX*64;                  // guarded table
  float* rpb2g = rpb2a + 64;

  P.WBs = WBs; P.WBl = WBl; P.WBq = WBq; P.WBk = WBk; P.WBv = WBv;
  P.WBo = WBo; P.WB1 = WB1; P.WB2 = WB2;
  P.rpb2g = rpb2g;
  P.xTq = xTq; P.xTkv = xTkv; P.qb = qb; P.kb = kb; P.vT = vT; P.aob = aob;
  P.emb = emb; P.outp = (float*)d_out;

  hipLaunchKernelGGL(k_prep_s,   dim3(839),  dim3(256), 0, stream, P);
  hipLaunchKernelGGL(k_conv_s,   dim3(784),  dim3(256), 0, stream, P);
  hipLaunchKernelGGL(k_natten_s, dim3(1568), dim3(256), 0, stream, P);
  hipLaunchKernelGGL(k_out_s,    dim3(392),  dim3(256), 0, stream, P);
}

// Round 14
// 69.371 us; speedup vs baseline: 1.2018x; 1.0193x over previous
//
#include <hip/hip_runtime.h>
#include <math.h>

#define SS 112
#define HW (SS*SS)
#define NPIX (2*HW)   // B*S*S = 25088

typedef __bf16 v8bf __attribute__((ext_vector_type(8)));
typedef short  v8s  __attribute__((ext_vector_type(8)));
typedef float  v4f  __attribute__((ext_vector_type(4)));

__device__ __forceinline__ unsigned short f2bf(float f){
  unsigned u = __builtin_bit_cast(unsigned, f);
  u = (u + 0x7fffu + ((u >> 16) & 1u)) >> 16;
  return (unsigned short)u;
}
__device__ __forceinline__ unsigned cvt_pk_bf16(float lo, float hi){
  unsigned r;
  asm("v_cvt_pk_bf16_f32 %0, %1, %2" : "=v"(r) : "v"(lo), "v"(hi));
  return r;
}
__device__ __forceinline__ v8bf zero8(){
  v8s z = {0,0,0,0,0,0,0,0};
  return __builtin_bit_cast(v8bf, z);
}
__device__ __forceinline__ float gelu_fast(float x){
  float u = fmaf(0.044715f*x, x, 1.0f);
  float z = fminf(2.3021178f * x * u, 80.0f);
  float s = exp2f(z);
  return x * s * __builtin_amdgcn_rcpf(s + 1.0f);
}

struct Params {
  const float *xq, *xkv, *cws, *cwl, *Wq, *Wk, *Wv, *Wo, *W1, *W2, *rpb;
  const float *cbs, *g_s, *b_s, *cbl, *g_l, *b_l;
  const float *bq, *bk, *bv, *bo, *gn, *bn, *b1, *b2;
  unsigned short *WBs, *WBl, *WBq, *WBk, *WBv, *WBo, *WB1, *WB2;
  float *rpb2g;
  unsigned short *xTq, *xTkv, *qb, *kb, *vT;
  float *emb, *outp;
};

__device__ __forceinline__ void pack_wconv(const float* __restrict__ w,
                                           unsigned short* __restrict__ WB, int idx){
  int lane = idx & 63, tslot = (idx >> 6) & 3, kk = idx >> 8;
  int tap = kk >> 1;
  int ic0 = ((kk & 1) << 5) + ((lane >> 4) << 3);
  int oc  = tslot*16 + (lane & 15);
  union { unsigned short u[8]; uint4 q; } pk;
  #pragma unroll
  for (int i = 0; i < 8; ++i) pk.u[i] = f2bf(w[(oc*64 + ic0 + i)*9 + tap]);
  ((uint4*)WB)[idx] = pk.q;
}
__device__ __forceinline__ void pack_wlin(const float* __restrict__ W,
                                          unsigned short* __restrict__ WB,
                                          int N, int idx){
  int lane = idx & 63;
  int tmp = idx >> 6;
  int tiles = N >> 4;
  int tslot = tmp % tiles;
  int kk = tmp / tiles;
  int k0 = kk*32 + ((lane >> 4) << 3);
  int oc = tslot*16 + (lane & 15);
  union { unsigned short u[8]; uint4 q; } pk;
  #pragma unroll
  for (int i = 0; i < 8; ++i) pk.u[i] = f2bf(W[(size_t)(k0 + i)*N + oc]);
  ((uint4*)WB)[idx] = pk.q;
}

// =============== kernel 1: weight packs + x transpose (grid 839) ============
__global__ __launch_bounds__(256) void k_prep_s(Params P)
{
  __shared__ float tile[64][68];
  const int u = blockIdx.x, tid = threadIdx.x;
  if (u >= 784){
    const int pu = u - 784;   // 0..54
    if      (pu < 18) pack_wconv(P.cws, P.WBs, pu*256 + tid);
    else if (pu < 36) pack_wconv(P.cwl, P.WBl, (pu-18)*256 + tid);
    else if (pu < 38) pack_wlin(P.Wq, P.WBq, 64,  (pu-36)*256 + tid);
    else if (pu < 40) pack_wlin(P.Wk, P.WBk, 64,  (pu-38)*256 + tid);
    else if (pu < 42) pack_wlin(P.Wv, P.WBv, 64,  (pu-40)*256 + tid);
    else if (pu < 44) pack_wlin(P.Wo, P.WBo, 64,  (pu-42)*256 + tid);
    else if (pu < 48) pack_wlin(P.W1, P.WB1, 128, (pu-44)*256 + tid);
    else if (pu < 52) pack_wlin(P.W2, P.WB2, 64,  (pu-48)*256 + tid);
    else {
      int idx = (pu-52)*256 + tid;
      if (idx < 4*169) P.rpb2g[idx] = P.rpb[idx] * 1.4426950408889634f;
    }
    return;
  }
  const int inst = u >= 392 ? 1 : 0;
  const float* x = inst ? P.xkv : P.xq;
  unsigned short* xT = inst ? P.xTkv : P.xTq;
  const int base = (u - inst*392) * 64;
  const int b = base / HW;
  const int r0 = base - b*HW;
  {
    const int cc = tid >> 2, xo = (tid & 3) << 4;
    const float* src = x + ((size_t)(b*64 + cc))*HW + r0 + xo;
    float4 v0 = ((const float4*)src)[0];
    float4 v1 = ((const float4*)src)[1];
    float4 v2 = ((const float4*)src)[2];
    float4 v3 = ((const float4*)src)[3];
    float* dst = &tile[cc][xo];
    ((float4*)dst)[0] = v0; ((float4*)dst)[1] = v1;
    ((float4*)dst)[2] = v2; ((float4*)dst)[3] = v3;
  }
  __syncthreads();
  {
    const int px = tid >> 2, co = (tid & 3) << 4;
    union { unsigned short uu[16]; uint4 q[2]; } pk;
    #pragma unroll
    for (int i = 0; i < 16; ++i) pk.uu[i] = f2bf(tile[co + i][px]);
    uint4* dst = (uint4*)(xT + ((size_t)(base + px))*64 + co);
    dst[0] = pk.q[0]; dst[1] = pk.q[1];
  }
}

// ======== kernel 2: conv(3x3 MFMA) + LN + projections (grid 784) ============
__global__ __launch_bounds__(256) void k_conv_s(Params P)
{
  __shared__ unsigned short nlds4[4][1024];
  const int tid = threadIdx.x;
  const int wid = tid >> 6, l = tid & 63;
  const int g = l >> 4, c = l & 15;
  unsigned short* nlds = nlds4[wid];
  const int u = (blockIdx.x & 7)*98 + (blockIdx.x >> 3);   // bijective: 784 = 8*98
  const int inst = u >= 392 ? 1 : 0;
  const int P0 = ((u - inst*392)*4 + wid) * 16;

  const unsigned short* xT  = inst ? P.xTkv : P.xTq;
  const unsigned short* WBc = inst ? P.WBl : P.WBs;
  const float* cb    = inst ? P.cbl : P.cbs;
  const float* gamma = inst ? P.g_l : P.g_s;
  const float* beta  = inst ? P.b_l : P.b_s;

  const int p = P0 + c;
  const int b = p / HW, r = p - b*HW;
  const int py = r / SS, pxx = r - py*SS;
  const int pb64 = b*HW;

  float cbv[4], gv[4], bev[4];
  #pragma unroll
  for (int t = 0; t < 4; ++t){
    cbv[t] = cb[c + 16*t]; gv[t] = gamma[c + 16*t]; bev[t] = beta[c + 16*t];
  }

  v4f acc[4];
  #pragma unroll
  for (int t = 0; t < 4; ++t) acc[t] = (v4f){cbv[t], cbv[t], cbv[t], cbv[t]};

  const int icg = g << 3;
  #pragma unroll
  for (int kk = 0; kk < 18; ++kk){
    const int tap = kk >> 1;
    const int dy = tap/3 - 1, dx = tap - (tap/3)*3 - 1;
    const int icof = ((kk & 1) << 5) + icg;
    int yy = py + dy, xx = pxx + dx;
    bool ok = ((unsigned)yy < SS) && ((unsigned)xx < SS);
    v8bf a = zero8();
    if (ok) a = *(const v8bf*)(xT + ((size_t)(pb64 + yy*SS + xx))*64 + icof);
    #pragma unroll
    for (int t = 0; t < 4; ++t){
      v8bf bfr = *(const v8bf*)(WBc + ((size_t)((kk*4 + t)*64 + l))*8);
      acc[t] = __builtin_amdgcn_mfma_f32_16x16x32_bf16(a, bfr, acc[t], 0, 0, 0);
    }
  }

  if (inst){
    #pragma unroll
    for (int t = 0; t < 4; ++t)
      #pragma unroll
      for (int r2 = 0; r2 < 4; ++r2)
        P.emb[((size_t)(P0 + 4*g + r2))*64 + c + 16*t] = acc[t][r2];
  }

  {
    float mean[4], inv[4];
    #pragma unroll
    for (int r2 = 0; r2 < 4; ++r2){
      float s = acc[0][r2] + acc[1][r2] + acc[2][r2] + acc[3][r2];
      s += __shfl_xor(s, 1, 64); s += __shfl_xor(s, 2, 64);
      s += __shfl_xor(s, 4, 64); s += __shfl_xor(s, 8, 64);
      mean[r2] = s * (1.f/64.f);
      float d0 = acc[0][r2] - mean[r2], d1 = acc[1][r2] - mean[r2];
      float d2 = acc[2][r2] - mean[r2], d3 = acc[3][r2] - mean[r2];
      float vs = d0*d0 + d1*d1 + d2*d2 + d3*d3;
      vs += __shfl_xor(vs, 1, 64); vs += __shfl_xor(vs, 2, 64);
      vs += __shfl_xor(vs, 4, 64); vs += __shfl_xor(vs, 8, 64);
      inv[r2] = rsqrtf(vs * (1.f/64.f) + 1e-5f);
    }
    #pragma unroll
    for (int t = 0; t < 4; ++t){
      int c16 = 2*t + (c >> 3);
      #pragma unroll
      for (int r2 = 0; r2 < 4; r2 += 2){
        int row0 = 4*g + r2, row1 = row0 + 1;
        float n0 = (acc[t][r2]   - mean[r2])   * inv[r2]   * gv[t] + bev[t];
        float n1 = (acc[t][r2+1] - mean[r2+1]) * inv[r2+1] * gv[t] + bev[t];
        unsigned w = cvt_pk_bf16(n0, n1);
        nlds[row0*64 + (((c16 ^ (row0 & 7)) << 3) | (c & 7))] = (unsigned short)(w & 0xffffu);
        nlds[row1*64 + (((c16 ^ (row1 & 7)) << 3) | (c & 7))] = (unsigned short)(w >> 16);
      }
    }
  }

  #pragma unroll
  for (int which = 0; which < 2; ++which){
    if (which == 1 && !inst) break;
    const unsigned short* WB = which ? P.WBv : (inst ? P.WBk : P.WBq);
    const float* bias        = which ? P.bv : (inst ? P.bk : P.bq);

    float pb[4];
    #pragma unroll
    for (int t = 0; t < 4; ++t) pb[t] = bias[c + 16*t];
    v4f pa[4];
    #pragma unroll
    for (int t = 0; t < 4; ++t) pa[t] = (v4f){pb[t], pb[t], pb[t], pb[t]};

    #pragma unroll
    for (int kk = 0; kk < 2; ++kk){
      v8bf av = *(const v8bf*)(nlds + c*64 + (((kk*4 + g) ^ (c & 7)) << 3));
      #pragma unroll
      for (int t = 0; t < 4; ++t){
        v8bf bfr = *(const v8bf*)(WB + ((size_t)((kk*4 + t)*64 + l))*8);
        pa[t] = __builtin_amdgcn_mfma_f32_16x16x32_bf16(av, bfr, pa[t], 0, 0, 0);
      }
    }
    if (which == 0){
      unsigned short* outp = inst ? P.kb : P.qb;
      #pragma unroll
      for (int t = 0; t < 4; ++t)
        #pragma unroll
        for (int r2 = 0; r2 < 4; r2 += 2){
          unsigned w = cvt_pk_bf16(pa[t][r2], pa[t][r2+1]);
          outp[((size_t)(P0 + 4*g + r2))*64 + c + 16*t]   = (unsigned short)(w & 0xffffu);
          outp[((size_t)(P0 + 4*g + r2+1))*64 + c + 16*t] = (unsigned short)(w >> 16);
        }
    } else {
      #pragma unroll
      for (int t = 0; t < 4; ++t){
        uint2 w2;
        w2.x = cvt_pk_bf16(pa[t][0], pa[t][1]);
        w2.y = cvt_pk_bf16(pa[t][2], pa[t][3]);
        *(uint2*)(P.vT + (size_t)(c + 16*t)*NPIX + (P0 + 4*g)) = w2;
      }
    }
  }
}

// ==== kernel 3: natten (16 px, wave=head) + wave-split out (grid 1568) ======
__global__ __launch_bounds__(256) void k_natten_out(Params P)
{
  __shared__ __align__(16) unsigned short alds[16*72];   // attn-out [px][ch]
  __shared__ __align__(16) unsigned short ylds[16*64];   // LN out, swizzled
  __shared__ __align__(16) unsigned short hlds[16*128];  // gelu(h), swizzled
  __shared__ float part_s[4][16];
  __shared__ float part_q[4][16];
  const int tid = threadIdx.x;
  const int wid = tid >> 6, l = tid & 63;
  const int h = wid;
  const int c = l & 15, g = l >> 4;
  const int u = (blockIdx.x & 7)*196 + (blockIdx.x >> 3); // bijective: 1568 = 8*196
  const int p0 = u * 16;
  const int b = p0 / HW, r0 = p0 - b*HW;
  const int i = r0 / SS, j0 = r0 - i*SS;

  // ---------------- natten phase (verbatim round-11, store -> LDS) ---------
  {
    const int si = min(max(i - 3, 0), SS - 7);
    const int aj = (min(max(j0 - 3, 0), SS - 22)) & ~7;
    const int oi = si - i + 6;
    const int pbase = b*HW;

    const int j   = j0 + c;
    const int sjp = min(max(j - 3, 0), SS - 7);
    const int adj = 8*g + (aj - sjp);
    const float* bp = P.rpb2g + h*169 + oi*13 + (8*g + aj - j + 6);

    v8bf bq = zero8();
    if (g < 2) bq = *(const v8bf*)(P.qb + (size_t)(p0 + c)*64 + h*16 + 8*g);

    float lt[14][4];
    const int arow = 8*(c >> 2) + (c & 3);
    #pragma unroll
    for (int tau = 0; tau < 14; ++tau){
      const int t = tau >> 1;
      int kpix = pbase + (si + t)*SS + aj + arow + 4*(tau & 1);
      kpix = min(kpix, NPIX - 1);
      v8bf ak = zero8();
      if (g < 2) ak = *(const v8bf*)(P.kb + (size_t)kpix*64 + h*16 + 8*g);
      v4f a0 = {0.f,0.f,0.f,0.f};
      a0 = __builtin_amdgcn_mfma_f32_16x16x32_bf16(ak, bq, a0, 0, 0, 0);
      lt[tau][0]=a0[0]; lt[tau][1]=a0[1]; lt[tau][2]=a0[2]; lt[tau][3]=a0[3];
    }

    const float SC = 0.3606737602222409f;
    float mx4[4] = {-3e38f,-3e38f,-3e38f,-3e38f};
    #pragma unroll
    for (int tau = 0; tau < 14; ++tau){
      const int t = tau >> 1;
      #pragma unroll
      for (int r = 0; r < 4; ++r){
        const int cc = 4*(tau & 1) + r;
        float bias = bp[t*13 + cc];
        float lg = fmaf(lt[tau][r], SC, bias);
        lt[tau][r] = ((unsigned)(adj + cc) <= 6u) ? lg : -1e30f;
        mx4[r] = fmaxf(mx4[r], lt[tau][r]);
      }
    }
    float mx = fmaxf(fmaxf(mx4[0], mx4[1]), fmaxf(mx4[2], mx4[3]));
    mx = fmaxf(mx, __shfl_xor(mx, 16, 64));
    mx = fmaxf(mx, __shfl_xor(mx, 32, 64));
    float es4[4] = {0.f,0.f,0.f,0.f};
    #pragma unroll
    for (int tau = 0; tau < 14; ++tau)
      #pragma unroll
      for (int r = 0; r < 4; ++r){
        float pexp = exp2f(lt[tau][r] - mx);
        lt[tau][r] = pexp;
        es4[r] += pexp;
      }
    float es = (es4[0] + es4[1]) + (es4[2] + es4[3]);
    es += __shfl_xor(es, 16, 64);
    es += __shfl_xor(es, 32, 64);
    const float inv = 1.0f / es;

    const unsigned short* vrow = P.vT + (size_t)(h*16 + c)*NPIX;
    v4f oacc = {0.f,0.f,0.f,0.f};
    #pragma unroll
    for (int t = 0; t < 7; ++t){
      union { unsigned w[4]; v8bf bf; } pa;
      pa.w[0] = cvt_pk_bf16(lt[2*t][0]*inv,   lt[2*t][1]*inv);
      pa.w[1] = cvt_pk_bf16(lt[2*t][2]*inv,   lt[2*t][3]*inv);
      pa.w[2] = cvt_pk_bf16(lt[2*t+1][0]*inv, lt[2*t+1][1]*inv);
      pa.w[3] = cvt_pk_bf16(lt[2*t+1][2]*inv, lt[2*t+1][3]*inv);
      int vpixb = pbase + (si + t)*SS + aj + 8*g;
      vpixb = min(vpixb, NPIX - 8);
      v8bf bv = *(const v8bf*)(vrow + vpixb);
      oacc = __builtin_amdgcn_mfma_f32_16x16x32_bf16(pa.bf, bv, oacc, 0, 0, 0);
    }

    #pragma unroll
    for (int r = 0; r < 4; r += 2){
      unsigned w = cvt_pk_bf16(oacc[r], oacc[r+1]);
      alds[(4*g + r)*72   + h*16 + c] = (unsigned short)(w & 0xffffu);
      alds[(4*g + r+1)*72 + h*16 + c] = (unsigned short)(w >> 16);
    }
  }
  __syncthreads();

  // ---------------- out phase: wave wid owns output-channel tile wid -------
  const int ijb = p0 - b*HW;
  const int cw = c + 16*wid;        // this wave's output channel

  // att = alds @ Wo (tile wid) + bo + emb
  v4f att;
  {
    float bb = P.bo[cw];
    #pragma unroll
    for (int r = 0; r < 4; ++r)
      att[r] = bb + P.emb[((size_t)(p0 + 4*g + r))*64 + cw];
    #pragma unroll
    for (int kk = 0; kk < 2; ++kk){
      v8bf a = *(const v8bf*)(alds + c*72 + kk*32 + 8*g);
      v8bf bfr = *(const v8bf*)(P.WBo + ((size_t)((kk*4 + wid)*64 + l))*8);
      att = __builtin_amdgcn_mfma_f32_16x16x32_bf16(a, bfr, att, 0, 0, 0);
    }
  }

  // cross-wave LayerNorm: partials (sum, sumsq) per pixel row
  {
    float s4[4], q4[4];
    #pragma unroll
    for (int r = 0; r < 4; ++r){
      float s = att[r], q = att[r]*att[r];
      s += __shfl_xor(s, 1, 64); q += __shfl_xor(q, 1, 64);
      s += __shfl_xor(s, 2, 64); q += __shfl_xor(q, 2, 64);
      s += __shfl_xor(s, 4, 64); q += __shfl_xor(q, 4, 64);
      s += __shfl_xor(s, 8, 64); q += __shfl_xor(q, 8, 64);
      s4[r] = s; q4[r] = q;
    }
    if (c == 0){
      #pragma unroll
      for (int r = 0; r < 4; ++r){
        part_s[wid][4*g + r] = s4[r];
        part_q[wid][4*g + r] = q4[r];
      }
    }
  }
  __syncthreads();
  {
    float gv = P.gn[cw], bev = P.bn[cw];
    const int c16 = 2*wid + (c >> 3);
    #pragma unroll
    for (int r = 0; r < 4; r += 2){
      int row0 = 4*g + r, row1 = row0 + 1;
      float ts0 = part_s[0][row0] + part_s[1][row0] + part_s[2][row0] + part_s[3][row0];
      float tq0 = part_q[0][row0] + part_q[1][row0] + part_q[2][row0] + part_q[3][row0];
      float ts1 = part_s[0][row1] + part_s[1][row1] + part_s[2][row1] + part_s[3][row1];
      float tq1 = part_q[0][row1] + part_q[1][row1] + part_q[2][row1] + part_q[3][row1];
      float m0 = ts0 * (1.f/64.f), m1 = ts1 * (1.f/64.f);
      float v0 = tq0 * (1.f/64.f) - m0*m0;
      float v1 = tq1 * (1.f/64.f) - m1*m1;
      float i0 = rsqrtf(v0 + 1e-5f), i1 = rsqrtf(v1 + 1e-5f);
      float n0 = (att[r]   - m0) * i0 * gv + bev;
      float n1 = (att[r+1] - m1) * i1 * gv + bev;
      unsigned w = cvt_pk_bf16(n0, n1);
      ylds[row0*64 + (((c16 ^ (row0 & 7)) << 3) | (c & 7))] = (unsigned short)(w & 0xffffu);
      ylds[row1*64 + (((c16 ^ (row1 & 7)) << 3) | (c & 7))] = (unsigned short)(w >> 16);
    }
  }
  __syncthreads();

  // h = gelu(y @ W1 + b1): wave wid computes tiles tt = 2*wid, 2*wid+1
  {
    v4f hc[2];
    #pragma unroll
    for (int q = 0; q < 2; ++q){
      int tt = 2*wid + q;
      float bb = P.b1[c + 16*tt];
      hc[q] = (v4f){bb,bb,bb,bb};
    }
    #pragma unroll
    for (int kk = 0; kk < 2; ++kk){
      v8bf a = *(const v8bf*)(ylds + c*64 + (((kk*4 + g) ^ (c & 7)) << 3));
      #pragma unroll
      for (int q = 0; q < 2; ++q){
        int tt = 2*wid + q;
        v8bf bfr = *(const v8bf*)(P.WB1 + ((size_t)((kk*8 + tt)*64 + l))*8);
        hc[q] = __builtin_amdgcn_mfma_f32_16x16x32_bf16(a, bfr, hc[q], 0, 0, 0);
      }
    }
    #pragma unroll
    for (int q = 0; q < 2; ++q){
      int tt = 2*wid + q;
      int chunk = 2*tt + (c >> 3);
      #pragma unroll
      for (int r = 0; r < 4; r += 2){
        int row0 = 4*g + r, row1 = row0 + 1;
        int swz0 = (chunk & 8) | ((chunk & 7) ^ (row0 & 7));
        int swz1 = (chunk & 8) | ((chunk & 7) ^ (row1 & 7));
        unsigned w = cvt_pk_bf16(gelu_fast(hc[q][r]), gelu_fast(hc[q][r+1]));
        hlds[row0*128 + swz0*8 + (c & 7)] = (unsigned short)(w & 0xffffu);
        hlds[row1*128 + swz1*8 + (c & 7)] = (unsigned short)(w >> 16);
      }
    }
  }
  __syncthreads();

  // x = h @ W2 (tile wid) + b2 + att -> NCHW
  {
    v4f xc;
    float bb = P.b2[cw];
    #pragma unroll
    for (int r = 0; r < 4; ++r) xc[r] = bb + att[r];
    #pragma unroll
    for (int kk = 0; kk < 4; ++kk){
      int chunk = 4*kk + g;
      int swz = (chunk & 8) | ((chunk & 7) ^ (c & 7));
      v8bf a = *(const v8bf*)(hlds + c*128 + swz*8);
      v8bf bfr = *(const v8bf*)(P.WB2 + ((size_t)((kk*4 + wid)*64 + l))*8);
      xc = __builtin_amdgcn_mfma_f32_16x16x32_bf16(a, bfr, xc, 0, 0, 0);
    }
    *(float4*)(P.outp + ((size_t)(b*64 + cw))*HW + ijb + 4*g) =
        __builtin_bit_cast(float4, xc);
  }
}

extern "C" void kernel_launch(void* const* d_in, const int* in_sizes, int n_in,
                              void* d_out, int out_size, void* d_ws, size_t ws_size,
                              hipStream_t stream) {
  Params P;
  P.xq  = (const float*)d_in[0];
  P.xkv = (const float*)d_in[1];
  P.cws = (const float*)d_in[2];
  P.cbs = (const float*)d_in[3];
  P.cwl = (const float*)d_in[4];
  P.cbl = (const float*)d_in[5];
  P.g_s = (const float*)d_in[6];
  P.b_s = (const float*)d_in[7];
  P.g_l = (const float*)d_in[8];
  P.b_l = (const float*)d_in[9];
  P.Wq  = (const float*)d_in[10];
  P.bq  = (const float*)d_in[11];
  P.Wk  = (const float*)d_in[12];
  P.bk  = (const float*)d_in[13];
  P.Wv  = (const float*)d_in[14];
  P.bv  = (const float*)d_in[15];
  P.Wo  = (const float*)d_in[16];
  P.bo  = (const float*)d_in[17];
  P.rpb = (const float*)d_in[18];
  P.gn  = (const float*)d_in[19];
  P.bn  = (const float*)d_in[20];
  P.W1  = (const float*)d_in[21];
  P.b1  = (const float*)d_in[22];
  P.W2  = (const float*)d_in[23];
  P.b2  = (const float*)d_in[24];

  unsigned short* xTq  = (unsigned short*)d_ws;          // NPIX*64
  unsigned short* xTkv = xTq  + (size_t)NPIX*64;
  unsigned short* WBs  = xTkv + (size_t)NPIX*64;         // 36864
  unsigned short* WBl  = WBs  + 36864;
  unsigned short* WBq  = WBl  + 36864;                   // 4096
  unsigned short* WBk  = WBq  + 4096;
  unsigned short* WBv  = WBk  + 4096;
  unsigned short* WBo  = WBv  + 4096;
  unsigned short* WB1  = WBo  + 4096;                    // 8192
  unsigned short* WB2  = WB1  + 8192;                    // 8192
  unsigned short* qb   = WB2  + 8192;                    // NPIX*64 bf16
  unsigned short* kb   = qb   + (size_t)NPIX*64;
  unsigned short* vT   = kb   + (size_t)NPIX*64;         // transposed [64][NPIX]
  float* emb   = (float*)(vT + (size_t)NPIX*64);         // NPIX*64 f32
  float* rpb2a = emb + (size_t)NPIX*64;                  // guarded table
  float* rpb2g = rpb2a + 64;

  P.WBs = WBs; P.WBl = WBl; P.WBq = WBq; P.WBk = WBk; P.WBv = WBv;
  P.WBo = WBo; P.WB1 = WB1; P.WB2 = WB2;
  P.rpb2g = rpb2g;
  P.xTq = xTq; P.xTkv = xTkv; P.qb = qb; P.kb = kb; P.vT = vT;
  P.emb = emb; P.outp = (float*)d_out;

  hipLaunchKernelGGL(k_prep_s,     dim3(839),  dim3(256), 0, stream, P);
  hipLaunchKernelGGL(k_conv_s,     dim3(784),  dim3(256), 0, stream, P);
  hipLaunchKernelGGL(k_natten_out, dim3(1568), dim3(256), 0, stream, P);
}

// Round 15
// 69.299 us; speedup vs baseline: 1.2030x; 1.0010x over previous
//
#include <hip/hip_runtime.h>
#include <math.h>

#define SS 112
#define HW (SS*SS)
#define NPIX (2*HW)   // B*S*S = 25088

typedef __bf16 v8bf __attribute__((ext_vector_type(8)));
typedef short  v8s  __attribute__((ext_vector_type(8)));
typedef float  v4f  __attribute__((ext_vector_type(4)));

__device__ __forceinline__ unsigned short f2bf(float f){
  unsigned u = __builtin_bit_cast(unsigned, f);
  u = (u + 0x7fffu + ((u >> 16) & 1u)) >> 16;
  return (unsigned short)u;
}
__device__ __forceinline__ float bf2f(unsigned short h){
  unsigned u = ((unsigned)h) << 16;
  return __builtin_bit_cast(float, u);
}
__device__ __forceinline__ unsigned cvt_pk_bf16(float lo, float hi){
  unsigned r;
  asm("v_cvt_pk_bf16_f32 %0, %1, %2" : "=v"(r) : "v"(lo), "v"(hi));
  return r;
}
__device__ __forceinline__ v8bf zero8(){
  v8s z = {0,0,0,0,0,0,0,0};
  return __builtin_bit_cast(v8bf, z);
}
__device__ __forceinline__ float gelu_fast(float x){
  float u = fmaf(0.044715f*x, x, 1.0f);
  float z = fminf(2.3021178f * x * u, 80.0f);
  float s = exp2f(z);
  return x * s * __builtin_amdgcn_rcpf(s + 1.0f);
}

struct Params {
  const float *xq, *xkv, *cws, *cwl, *Wq, *Wk, *Wv, *Wo, *W1, *W2, *rpb;
  const float *cbs, *g_s, *b_s, *cbl, *g_l, *b_l;
  const float *bq, *bk, *bv, *bo, *gn, *bn, *b1, *b2;
  unsigned short *WBs, *WBl, *WBq, *WBk, *WBv, *WBo, *WB1, *WB2;
  float *rpb2g;
  unsigned short *xTq, *xTkv, *qb, *kb, *vT, *embb;
  float *outp;
};

__device__ __forceinline__ void pack_wconv(const float* __restrict__ w,
                                           unsigned short* __restrict__ WB, int idx){
  int lane = idx & 63, tslot = (idx >> 6) & 3, kk = idx >> 8;
  int tap = kk >> 1;
  int ic0 = ((kk & 1) << 5) + ((lane >> 4) << 3);
  int oc  = tslot*16 + (lane & 15);
  union { unsigned short u[8]; uint4 q; } pk;
  #pragma unroll
  for (int i = 0; i < 8; ++i) pk.u[i] = f2bf(w[(oc*64 + ic0 + i)*9 + tap]);
  ((uint4*)WB)[idx] = pk.q;
}
__device__ __forceinline__ void pack_wlin(const float* __restrict__ W,
                                          unsigned short* __restrict__ WB,
                                          int N, int idx){
  int lane = idx & 63;
  int tmp = idx >> 6;
  int tiles = N >> 4;
  int tslot = tmp % tiles;
  int kk = tmp / tiles;
  int k0 = kk*32 + ((lane >> 4) << 3);
  int oc = tslot*16 + (lane & 15);
  union { unsigned short u[8]; uint4 q; } pk;
  #pragma unroll
  for (int i = 0; i < 8; ++i) pk.u[i] = f2bf(W[(size_t)(k0 + i)*N + oc]);
  ((uint4*)WB)[idx] = pk.q;
}

// =============== kernel 1: weight packs + x transpose (grid 839) ============
__global__ __launch_bounds__(256) void k_prep_s(Params P)
{
  __shared__ float tile[64][68];
  const int u = blockIdx.x, tid = threadIdx.x;
  if (u >= 784){
    const int pu = u - 784;   // 0..54
    if      (pu < 18) pack_wconv(P.cws, P.WBs, pu*256 + tid);
    else if (pu < 36) pack_wconv(P.cwl, P.WBl, (pu-18)*256 + tid);
    else if (pu < 38) pack_wlin(P.Wq, P.WBq, 64,  (pu-36)*256 + tid);
    else if (pu < 40) pack_wlin(P.Wk, P.WBk, 64,  (pu-38)*256 + tid);
    else if (pu < 42) pack_wlin(P.Wv, P.WBv, 64,  (pu-40)*256 + tid);
    else if (pu < 44) pack_wlin(P.Wo, P.WBo, 64,  (pu-42)*256 + tid);
    else if (pu < 48) pack_wlin(P.W1, P.WB1, 128, (pu-44)*256 + tid);
    else if (pu < 52) pack_wlin(P.W2, P.WB2, 64,  (pu-48)*256 + tid);
    else {
      int idx = (pu-52)*256 + tid;
      if (idx < 4*169) P.rpb2g[idx] = P.rpb[idx] * 1.4426950408889634f;
    }
    return;
  }
  const int inst = u >= 392 ? 1 : 0;
  const float* x = inst ? P.xkv : P.xq;
  unsigned short* xT = inst ? P.xTkv : P.xTq;
  const int base = (u - inst*392) * 64;
  const int b = base / HW;
  const int r0 = base - b*HW;
  {
    const int cc = tid >> 2, xo = (tid & 3) << 4;
    const float* src = x + ((size_t)(b*64 + cc))*HW + r0 + xo;
    float4 v0 = ((const float4*)src)[0];
    float4 v1 = ((const float4*)src)[1];
    float4 v2 = ((const float4*)src)[2];
    float4 v3 = ((const float4*)src)[3];
    float* dst = &tile[cc][xo];
    ((float4*)dst)[0] = v0; ((float4*)dst)[1] = v1;
    ((float4*)dst)[2] = v2; ((float4*)dst)[3] = v3;
  }
  __syncthreads();
  {
    const int px = tid >> 2, co = (tid & 3) << 4;
    union { unsigned short uu[16]; uint4 q[2]; } pk;
    #pragma unroll
    for (int i = 0; i < 16; ++i) pk.uu[i] = f2bf(tile[co + i][px]);
    uint4* dst = (uint4*)(xT + ((size_t)(base + px))*64 + co);
    dst[0] = pk.q[0]; dst[1] = pk.q[1];
  }
}

// ======== kernel 2: conv(3x3 MFMA) + LN + projections (grid 784) ============
__global__ __launch_bounds__(256) void k_conv_s(Params P)
{
  __shared__ unsigned short nlds4[4][1024];
  const int tid = threadIdx.x;
  const int wid = tid >> 6, l = tid & 63;
  const int g = l >> 4, c = l & 15;
  unsigned short* nlds = nlds4[wid];
  const int u = (blockIdx.x & 7)*98 + (blockIdx.x >> 3);   // bijective: 784 = 8*98
  const int inst = u >= 392 ? 1 : 0;
  const int P0 = ((u - inst*392)*4 + wid) * 16;

  const unsigned short* xT  = inst ? P.xTkv : P.xTq;
  const unsigned short* WBc = inst ? P.WBl : P.WBs;
  const float* cb    = inst ? P.cbl : P.cbs;
  const float* gamma = inst ? P.g_l : P.g_s;
  const float* beta  = inst ? P.b_l : P.b_s;

  const int p = P0 + c;
  const int b = p / HW, r = p - b*HW;
  const int py = r / SS, pxx = r - py*SS;
  const int pb64 = b*HW;

  float cbv[4], gv[4], bev[4];
  #pragma unroll
  for (int t = 0; t < 4; ++t){
    cbv[t] = cb[c + 16*t]; gv[t] = gamma[c + 16*t]; bev[t] = beta[c + 16*t];
  }

  v4f acc[4];
  #pragma unroll
  for (int t = 0; t < 4; ++t) acc[t] = (v4f){cbv[t], cbv[t], cbv[t], cbv[t]};

  const int icg = g << 3;
  #pragma unroll
  for (int kk = 0; kk < 18; ++kk){
    const int tap = kk >> 1;
    const int dy = tap/3 - 1, dx = tap - (tap/3)*3 - 1;
    const int icof = ((kk & 1) << 5) + icg;
    int yy = py + dy, xx = pxx + dx;
    bool ok = ((unsigned)yy < SS) && ((unsigned)xx < SS);
    v8bf a = zero8();
    if (ok) a = *(const v8bf*)(xT + ((size_t)(pb64 + yy*SS + xx))*64 + icof);
    #pragma unroll
    for (int t = 0; t < 4; ++t){
      v8bf bfr = *(const v8bf*)(WBc + ((size_t)((kk*4 + t)*64 + l))*8);
      acc[t] = __builtin_amdgcn_mfma_f32_16x16x32_bf16(a, bfr, acc[t], 0, 0, 0);
    }
  }

  if (inst){
    #pragma unroll
    for (int t = 0; t < 4; ++t)
      #pragma unroll
      for (int r2 = 0; r2 < 4; r2 += 2){
        unsigned w = cvt_pk_bf16(acc[t][r2], acc[t][r2+1]);
        P.embb[((size_t)(P0 + 4*g + r2))*64 + c + 16*t]   = (unsigned short)(w & 0xffffu);
        P.embb[((size_t)(P0 + 4*g + r2+1))*64 + c + 16*t] = (unsigned short)(w >> 16);
      }
  }

  {
    float mean[4], inv[4];
    #pragma unroll
    for (int r2 = 0; r2 < 4; ++r2){
      float s = acc[0][r2] + acc[1][r2] + acc[2][r2] + acc[3][r2];
      s += __shfl_xor(s, 1, 64); s += __shfl_xor(s, 2, 64);
      s += __shfl_xor(s, 4, 64); s += __shfl_xor(s, 8, 64);
      mean[r2] = s * (1.f/64.f);
      float d0 = acc[0][r2] - mean[r2], d1 = acc[1][r2] - mean[r2];
      float d2 = acc[2][r2] - mean[r2], d3 = acc[3][r2] - mean[r2];
      float vs = d0*d0 + d1*d1 + d2*d2 + d3*d3;
      vs += __shfl_xor(vs, 1, 64); vs += __shfl_xor(vs, 2, 64);
      vs += __shfl_xor(vs, 4, 64); vs += __shfl_xor(vs, 8, 64);
      inv[r2] = rsqrtf(vs * (1.f/64.f) + 1e-5f);
    }
    #pragma unroll
    for (int t = 0; t < 4; ++t){
      int c16 = 2*t + (c >> 3);
      #pragma unroll
      for (int r2 = 0; r2 < 4; r2 += 2){
        int row0 = 4*g + r2, row1 = row0 + 1;
        float n0 = (acc[t][r2]   - mean[r2])   * inv[r2]   * gv[t] + bev[t];
        float n1 = (acc[t][r2+1] - mean[r2+1]) * inv[r2+1] * gv[t] + bev[t];
        unsigned w = cvt_pk_bf16(n0, n1);
        nlds[row0*64 + (((c16 ^ (row0 & 7)) << 3) | (c & 7))] = (unsigned short)(w & 0xffffu);
        nlds[row1*64 + (((c16 ^ (row1 & 7)) << 3) | (c & 7))] = (unsigned short)(w >> 16);
      }
    }
  }

  // hoist A-fragment reads (identical across which)
  v8bf av01[2];
  #pragma unroll
  for (int kk = 0; kk < 2; ++kk)
    av01[kk] = *(const v8bf*)(nlds + c*64 + (((kk*4 + g) ^ (c & 7)) << 3));

  #pragma unroll
  for (int which = 0; which < 2; ++which){
    if (which == 1 && !inst) break;
    const unsigned short* WB = which ? P.WBv : (inst ? P.WBk : P.WBq);
    const float* bias        = which ? P.bv : (inst ? P.bk : P.bq);

    float pb[4];
    #pragma unroll
    for (int t = 0; t < 4; ++t) pb[t] = bias[c + 16*t];
    v4f pa[4];
    #pragma unroll
    for (int t = 0; t < 4; ++t) pa[t] = (v4f){pb[t], pb[t], pb[t], pb[t]};

    #pragma unroll
    for (int kk = 0; kk < 2; ++kk){
      #pragma unroll
      for (int t = 0; t < 4; ++t){
        v8bf bfr = *(const v8bf*)(WB + ((size_t)((kk*4 + t)*64 + l))*8);
        pa[t] = __builtin_amdgcn_mfma_f32_16x16x32_bf16(av01[kk], bfr, pa[t], 0, 0, 0);
      }
    }
    if (which == 0){
      unsigned short* outp = inst ? P.kb : P.qb;
      #pragma unroll
      for (int t = 0; t < 4; ++t)
        #pragma unroll
        for (int r2 = 0; r2 < 4; r2 += 2){
          unsigned w = cvt_pk_bf16(pa[t][r2], pa[t][r2+1]);
          outp[((size_t)(P0 + 4*g + r2))*64 + c + 16*t]   = (unsigned short)(w & 0xffffu);
          outp[((size_t)(P0 + 4*g + r2+1))*64 + c + 16*t] = (unsigned short)(w >> 16);
        }
    } else {
      #pragma unroll
      for (int t = 0; t < 4; ++t){
        uint2 w2;
        w2.x = cvt_pk_bf16(pa[t][0], pa[t][1]);
        w2.y = cvt_pk_bf16(pa[t][2], pa[t][3]);
        *(uint2*)(P.vT + (size_t)(c + 16*t)*NPIX + (P0 + 4*g)) = w2;
      }
    }
  }
}

// ==== kernel 3: natten (16 px, wave=head) + wave-split out (grid 1568) ======
__global__ __launch_bounds__(256) void k_natten_out(Params P)
{
  __shared__ __align__(16) unsigned short alds[16*72];   // attn-out [px][ch]
  __shared__ __align__(16) unsigned short ylds[16*64];   // LN out, swizzled
  __shared__ __align__(16) unsigned short hlds[16*128];  // gelu(h), swizzled
  __shared__ float part_s[4][16];
  __shared__ float part_q[4][16];
  const int tid = threadIdx.x;
  const int wid = tid >> 6, l = tid & 63;
  const int h = wid;
  const int c = l & 15, g = l >> 4;
  const int u = (blockIdx.x & 7)*196 + (blockIdx.x >> 3); // bijective: 1568 = 8*196
  const int p0 = u * 16;
  const int b = p0 / HW, r0 = p0 - b*HW;
  const int i = r0 / SS, j0 = r0 - i*SS;

  // ---------------- natten phase ----------------
  {
    const int si = min(max(i - 3, 0), SS - 7);
    const int aj = (min(max(j0 - 3, 0), SS - 22)) & ~7;
    const int oi = si - i + 6;
    const int pbase = b*HW;

    const int j   = j0 + c;
    const int sjp = min(max(j - 3, 0), SS - 7);
    const int adj = 8*g + (aj - sjp);
    const float* bp = P.rpb2g + h*169 + oi*13 + (8*g + aj - j + 6);

    v8bf bq = zero8();
    if (g < 2) bq = *(const v8bf*)(P.qb + (size_t)(p0 + c)*64 + h*16 + 8*g);

    float lt[14][4];
    const int arow = 8*(c >> 2) + (c & 3);
    #pragma unroll
    for (int tau = 0; tau < 14; ++tau){
      const int t = tau >> 1;
      int kpix = pbase + (si + t)*SS + aj + arow + 4*(tau & 1);
      kpix = min(kpix, NPIX - 1);
      v8bf ak = zero8();
      if (g < 2) ak = *(const v8bf*)(P.kb + (size_t)kpix*64 + h*16 + 8*g);
      v4f a0 = {0.f,0.f,0.f,0.f};
      a0 = __builtin_amdgcn_mfma_f32_16x16x32_bf16(ak, bq, a0, 0, 0, 0);
      lt[tau][0]=a0[0]; lt[tau][1]=a0[1]; lt[tau][2]=a0[2]; lt[tau][3]=a0[3];
    }

    const float SC = 0.3606737602222409f;
    float mx4[4] = {-3e38f,-3e38f,-3e38f,-3e38f};
    #pragma unroll
    for (int tau = 0; tau < 14; ++tau){
      const int t = tau >> 1;
      #pragma unroll
      for (int r = 0; r < 4; ++r){
        const int cc = 4*(tau & 1) + r;
        float bias = bp[t*13 + cc];
        float lg = fmaf(lt[tau][r], SC, bias);
        lt[tau][r] = ((unsigned)(adj + cc) <= 6u) ? lg : -1e30f;
        mx4[r] = fmaxf(mx4[r], lt[tau][r]);
      }
    }
    float mx = fmaxf(fmaxf(mx4[0], mx4[1]), fmaxf(mx4[2], mx4[3]));
    mx = fmaxf(mx, __shfl_xor(mx, 16, 64));
    mx = fmaxf(mx, __shfl_xor(mx, 32, 64));
    float es4[4] = {0.f,0.f,0.f,0.f};
    #pragma unroll
    for (int tau = 0; tau < 14; ++tau)
      #pragma unroll
      for (int r = 0; r < 4; ++r){
        float pexp = exp2f(lt[tau][r] - mx);
        lt[tau][r] = pexp;
        es4[r] += pexp;
      }
    float es = (es4[0] + es4[1]) + (es4[2] + es4[3]);
    es += __shfl_xor(es, 16, 64);
    es += __shfl_xor(es, 32, 64);
    const float inv = 1.0f / es;

    const unsigned short* vrow = P.vT + (size_t)(h*16 + c)*NPIX;
    v4f oacc = {0.f,0.f,0.f,0.f};
    #pragma unroll
    for (int t = 0; t < 7; ++t){
      union { unsigned w[4]; v8bf bf; } pa;
      pa.w[0] = cvt_pk_bf16(lt[2*t][0]*inv,   lt[2*t][1]*inv);
      pa.w[1] = cvt_pk_bf16(lt[2*t][2]*inv,   lt[2*t][3]*inv);
      pa.w[2] = cvt_pk_bf16(lt[2*t+1][0]*inv, lt[2*t+1][1]*inv);
      pa.w[3] = cvt_pk_bf16(lt[2*t+1][2]*inv, lt[2*t+1][3]*inv);
      int vpixb = pbase + (si + t)*SS + aj + 8*g;
      vpixb = min(vpixb, NPIX - 8);
      v8bf bv = *(const v8bf*)(vrow + vpixb);
      oacc = __builtin_amdgcn_mfma_f32_16x16x32_bf16(pa.bf, bv, oacc, 0, 0, 0);
    }

    #pragma unroll
    for (int r = 0; r < 4; r += 2){
      unsigned w = cvt_pk_bf16(oacc[r], oacc[r+1]);
      alds[(4*g + r)*72   + h*16 + c] = (unsigned short)(w & 0xffffu);
      alds[(4*g + r+1)*72 + h*16 + c] = (unsigned short)(w >> 16);
    }
  }
  __syncthreads();

  // ---------------- out phase: wave wid owns output-channel tile wid -------
  const int ijb = p0 - b*HW;
  const int cw = c + 16*wid;

  v4f att;
  {
    float bb = P.bo[cw];
    #pragma unroll
    for (int r = 0; r < 4; ++r)
      att[r] = bb + bf2f(P.embb[((size_t)(p0 + 4*g + r))*64 + cw]);
    #pragma unroll
    for (int kk = 0; kk < 2; ++kk){
      v8bf a = *(const v8bf*)(alds + c*72 + kk*32 + 8*g);
      v8bf bfr = *(const v8bf*)(P.WBo + ((size_t)((kk*4 + wid)*64 + l))*8);
      att = __builtin_amdgcn_mfma_f32_16x16x32_bf16(a, bfr, att, 0, 0, 0);
    }
  }

  {
    float s4[4], q4[4];
    #pragma unroll
    for (int r = 0; r < 4; ++r){
      float s = att[r], q = att[r]*att[r];
      s += __shfl_xor(s, 1, 64); q += __shfl_xor(q, 1, 64);
      s += __shfl_xor(s, 2, 64); q += __shfl_xor(q, 2, 64);
      s += __shfl_xor(s, 4, 64); q += __shfl_xor(q, 4, 64);
      s += __shfl_xor(s, 8, 64); q += __shfl_xor(q, 8, 64);
      s4[r] = s; q4[r] = q;
    }
    if (c == 0){
      #pragma unroll
      for (int r = 0; r < 4; ++r){
        part_s[wid][4*g + r] = s4[r];
        part_q[wid][4*g + r] = q4[r];
      }
    }
  }
  __syncthreads();
  {
    float gv = P.gn[cw], bev = P.bn[cw];
    const int c16 = 2*wid + (c >> 3);
    #pragma unroll
    for (int r = 0; r < 4; r += 2){
      int row0 = 4*g + r, row1 = row0 + 1;
      float ts0 = part_s[0][row0] + part_s[1][row0] + part_s[2][row0] + part_s[3][row0];
      float tq0 = part_q[0][row0] + part_q[1][row0] + part_q[2][row0] + part_q[3][row0];
      float ts1 = part_s[0][row1] + part_s[1][row1] + part_s[2][row1] + part_s[3][row1];
      float tq1 = part_q[0][row1] + part_q[1][row1] + part_q[2][row1] + part_q[3][row1];
      float m0 = ts0 * (1.f/64.f), m1 = ts1 * (1.f/64.f);
      float v0 = tq0 * (1.f/64.f) - m0*m0;
      float v1 = tq1 * (1.f/64.f) - m1*m1;
      float i0 = rsqrtf(v0 + 1e-5f), i1 = rsqrtf(v1 + 1e-5f);
      float n0 = (att[r]   - m0) * i0 * gv + bev;
      float n1 = (att[r+1] - m1) * i1 * gv + bev;
      unsigned w = cvt_pk_bf16(n0, n1);
      ylds[row0*64 + (((c16 ^ (row0 & 7)) << 3) | (c & 7))] = (unsigned short)(w & 0xffffu);
      ylds[row1*64 + (((c16 ^ (row1 & 7)) << 3) | (c & 7))] = (unsigned short)(w >> 16);
    }
  }
  __syncthreads();

  {
    v4f hc[2];
    #pragma unroll
    for (int q = 0; q < 2; ++q){
      int tt = 2*wid + q;
      float bb = P.b1[c + 16*tt];
      hc[q] = (v4f){bb,bb,bb,bb};
    }
    #pragma unroll
    for (int kk = 0; kk < 2; ++kk){
      v8bf a = *(const v8bf*)(ylds + c*64 + (((kk*4 + g) ^ (c & 7)) << 3));
      #pragma unroll
      for (int q = 0; q < 2; ++q){
        int tt = 2*wid + q;
        v8bf bfr = *(const v8bf*)(P.WB1 + ((size_t)((kk*8 + tt)*64 + l))*8);
        hc[q] = __builtin_amdgcn_mfma_f32_16x16x32_bf16(a, bfr, hc[q], 0, 0, 0);
      }
    }
    #pragma unroll
    for (int q = 0; q < 2; ++q){
      int tt = 2*wid + q;
      int chunk = 2*tt + (c >> 3);
      #pragma unroll
      for (int r = 0; r < 4; r += 2){
        int row0 = 4*g + r, row1 = row0 + 1;
        int swz0 = (chunk & 8) | ((chunk & 7) ^ (row0 & 7));
        int swz1 = (chunk & 8) | ((chunk & 7) ^ (row1 & 7));
        unsigned w = cvt_pk_bf16(gelu_fast(hc[q][r]), gelu_fast(hc[q][r+1]));
        hlds[row0*128 + swz0*8 + (c & 7)] = (unsigned short)(w & 0xffffu);
        hlds[row1*128 + swz1*8 + (c & 7)] = (unsigned short)(w >> 16);
      }
    }
  }
  __syncthreads();

  {
    v4f xc;
    float bb = P.b2[cw];
    #pragma unroll
    for (int r = 0; r < 4; ++r) xc[r] = bb + att[r];
    #pragma unroll
    for (int kk = 0; kk < 4; ++kk){
      int chunk = 4*kk + g;
      int swz = (chunk & 8) | ((chunk & 7) ^ (c & 7));
      v8bf a = *(const v8bf*)(hlds + c*128 + swz*8);
      v8bf bfr = *(const v8bf*)(P.WB2 + ((size_t)((kk*4 + wid)*64 + l))*8);
      xc = __builtin_amdgcn_mfma_f32_16x16x32_bf16(a, bfr, xc, 0, 0, 0);
    }
    *(float4*)(P.outp + ((size_t)(b*64 + cw))*HW + ijb + 4*g) =
        __builtin_bit_cast(float4, xc);
  }
}

extern "C" void kernel_launch(void* const* d_in, const int* in_sizes, int n_in,
                              void* d_out, int out_size, void* d_ws, size_t ws_size,
                              hipStream_t stream) {
  Params P;
  P.xq  = (const float*)d_in[0];
  P.xkv = (const float*)d_in[1];
  P.cws = (const float*)d_in[2];
  P.cbs = (const float*)d_in[3];
  P.cwl = (const float*)d_in[4];
  P.cbl = (const float*)d_in[5];
  P.g_s = (const float*)d_in[6];
  P.b_s = (const float*)d_in[7];
  P.g_l = (const float*)d_in[8];
  P.b_l = (const float*)d_in[9];
  P.Wq  = (const float*)d_in[10];
  P.bq  = (const float*)d_in[11];
  P.Wk  = (const float*)d_in[12];
  P.bk  = (const float*)d_in[13];
  P.Wv  = (const float*)d_in[14];
  P.bv  = (const float*)d_in[15];
  P.Wo  = (const float*)d_in[16];
  P.bo  = (const float*)d_in[17];
  P.rpb = (const float*)d_in[18];
  P.gn  = (const float*)d_in[19];
  P.bn  = (const float*)d_in[20];
  P.W1  = (const float*)d_in[21];
  P.b1  = (const float*)d_in[22];
  P.W2  = (const float*)d_in[23];
  P.b2  = (const float*)d_in[24];

  unsigned short* xTq  = (unsigned short*)d_ws;          // NPIX*64
  unsigned short* xTkv = xTq  + (size_t)NPIX*64;
  unsigned short* WBs  = xTkv + (size_t)NPIX*64;         // 36864
  unsigned short* WBl  = WBs  + 36864;
  unsigned short* WBq  = WBl  + 36864;                   // 4096
  unsigned short* WBk  = WBq  + 4096;
  unsigned short* WBv  = WBk  + 4096;
  unsigned short* WBo  = WBv  + 4096;
  unsigned short* WB1  = WBo  + 4096;                    // 8192
  unsigned short* WB2  = WB1  + 8192;                    // 8192
  unsigned short* qb   = WB2  + 8192;                    // NPIX*64 bf16
  unsigned short* kb   = qb   + (size_t)NPIX*64;
  unsigned short* vT   = kb   + (size_t)NPIX*64;         // transposed [64][NPIX]
  unsigned short* embb = vT   + (size_t)NPIX*64;         // NPIX*64 bf16
  float* rpb2a = (float*)(embb + (size_t)NPIX*64);       // guarded table
  float* rpb2g = rpb2a + 64;

  P.WBs = WBs; P.WBl = WBl; P.WBq = WBq; P.WBk = WBk; P.WBv = WBv;
  P.WBo = WBo; P.WB1 = WB1; P.WB2 = WB2;
  P.rpb2g = rpb2g;
  P.xTq = xTq; P.xTkv = xTkv; P.qb = qb; P.kb = kb; P.vT = vT; P.embb = embb;
  P.outp = (float*)d_out;

  hipLaunchKernelGGL(k_prep_s,     dim3(839),  dim3(256), 0, stream, P);
  hipLaunchKernelGGL(k_conv_s,     dim3(784),  dim3(256), 0, stream, P);
  hipLaunchKernelGGL(k_natten_out, dim3(1568), dim3(256), 0, stream, P);
}